// Round 5
// baseline (1161.911 us; speedup 1.0000x reference)
//
#include <hip/hip_runtime.h>

constexpr int NN   = 20000;
constexpr int EE   = 200000;
constexpr int IN_D = 500;
constexpr int HID  = 256;
constexpr int OUT_D= 16;
constexpr int MH   = 64;

// bf16 helpers (internal H storage only)
__device__ __forceinline__ float bf2f(unsigned short s) {
    return __uint_as_float((unsigned)s << 16);
}
__device__ __forceinline__ unsigned short f2bf(float f) {
    unsigned u = __float_as_uint(f);
    unsigned r = u + 0x7FFF + ((u >> 16) & 1);   // round-to-nearest-even
    return (unsigned short)(r >> 16);
}

// ===========================================================================
// CSR incidence build. inc entry = edge*2 + is_dst; inc2 entry = other node.
// ===========================================================================
__global__ __launch_bounds__(256) void k_deg(const int* __restrict__ ei, int* __restrict__ deg)
{
    int e = blockIdx.x * 256 + threadIdx.x;
    if (e < EE) {
        atomicAdd(deg + ei[e], 1);
        atomicAdd(deg + ei[EE + e], 1);
    }
}

// Parallel scan, 3 kernels. Block sums parked in dead H1 region.
__global__ __launch_bounds__(128) void k_scan_a(const int* __restrict__ deg,
                                                int* __restrict__ off, int* __restrict__ bsum)
{
    __shared__ int s[128];
    const int b = blockIdx.x, tid = threadIdx.x;
    const int n = b * 80 + tid;
    int v = (tid < 80) ? deg[n] : 0;
    s[tid] = v;
    __syncthreads();
    for (int o = 1; o < 128; o <<= 1) {
        int x = 0;
        if (tid >= o) x = s[tid - o];
        __syncthreads();
        if (tid >= o) s[tid] += x;
        __syncthreads();
    }
    if (tid < 80) off[n] = s[tid] - v;     // local exclusive prefix
    if (tid == 127) bsum[b] = s[127];      // block total
}

__global__ __launch_bounds__(256) void k_scan_b(int* __restrict__ bsum)
{
    __shared__ int s[256];
    const int tid = threadIdx.x;
    int v = (tid < 250) ? bsum[tid] : 0;
    s[tid] = v;
    __syncthreads();
    for (int o = 1; o < 256; o <<= 1) {
        int x = 0;
        if (tid >= o) x = s[tid - o];
        __syncthreads();
        if (tid >= o) s[tid] += x;
        __syncthreads();
    }
    if (tid < 250) bsum[tid] = s[tid] - v; // exclusive
}

__global__ __launch_bounds__(256) void k_scan_c(const int* __restrict__ bsum,
                                                int* __restrict__ off, int* __restrict__ cursor)
{
    const int n = blockIdx.x * 256 + threadIdx.x;
    if (n < NN) {
        int o = off[n] + bsum[n / 80];
        off[n] = o;
        cursor[n] = o;
    }
    if (n == 0) off[NN] = 2 * EE;
}

__global__ __launch_bounds__(256) void k_scatter(const int* __restrict__ ei,
                                                 int* __restrict__ cursor,
                                                 int* __restrict__ inc, int* __restrict__ inc2)
{
    int e = blockIdx.x * 256 + threadIdx.x;
    if (e < EE) {
        int s = ei[e], d = ei[EE + e];
        int p = atomicAdd(cursor + s, 1); inc[p] = e * 2;     inc2[p] = d;
        p = atomicAdd(cursor + d, 1);     inc[p] = e * 2 + 1; inc2[p] = s;
    }
}

// ===========================================================================
// k_mlp1: t1 = relu(x @ Win1.T + bin1).
// v2: 32 nodes/block, ALL 64 channels (8/thread) -> x read ONCE (40 MB).
// grid 625. Weights are L1/L2-resident broadcasts.
// ===========================================================================
__global__ __launch_bounds__(256) void k_mlp1(
    const float* __restrict__ x, const float* __restrict__ Win1, const float* __restrict__ bin1,
    float* __restrict__ t1)
{
    __shared__ float xs[32 * 101];
    const int tid = threadIdx.x;
    const int n  = tid >> 3;          // 0..31 node within tile
    const int c8 = tid & 7;           // 0..7 channel group (8 ch each)
    const int node0 = blockIdx.x * 32;
    const int g = node0 + n;

    float acc[8];
    #pragma unroll
    for (int i = 0; i < 8; ++i) acc[i] = 0.f;

    for (int j = 0; j < 5; ++j) {
        __syncthreads();
        for (int i = tid; i < 800; i += 256) {
            int nn = i / 25, k4 = i % 25;
            float4 v = ((const float4*)x)[(size_t)(node0 + nn) * 125 + j * 25 + k4];
            float* d = &xs[nn * 101 + k4 * 4];
            d[0] = v.x; d[1] = v.y; d[2] = v.z; d[3] = v.w;
        }
        __syncthreads();
        for (int kt = 0; kt < 25; ++kt) {
            float x0 = xs[n * 101 + kt * 4 + 0];
            float x1 = xs[n * 101 + kt * 4 + 1];
            float x2 = xs[n * 101 + kt * 4 + 2];
            float x3 = xs[n * 101 + kt * 4 + 3];
            #pragma unroll
            for (int cc = 0; cc < 8; ++cc) {
                const float* wr = Win1 + (size_t)(c8 * 8 + cc) * IN_D + j * 100 + kt * 4;
                acc[cc] += x0 * wr[0] + x1 * wr[1] + x2 * wr[2] + x3 * wr[3];
            }
        }
    }
    float* dst = t1 + (size_t)g * MH + c8 * 8;
    #pragma unroll
    for (int q = 0; q < 2; ++q) {
        float4 v;
        v.x = fmaxf(acc[q*4+0] + bin1[c8*8 + q*4+0], 0.f);
        v.y = fmaxf(acc[q*4+1] + bin1[c8*8 + q*4+1], 0.f);
        v.z = fmaxf(acc[q*4+2] + bin1[c8*8 + q*4+2], 0.f);
        v.w = fmaxf(acc[q*4+3] + bin1[c8*8 + q*4+3], 0.f);
        *(float4*)(dst + q * 4) = v;
    }
}

// ===========================================================================
// k_mlp2: h = t1 @ Win2.T + bin2.  grid (N/64, 4).  (unchanged)
// ===========================================================================
__global__ __launch_bounds__(256, 4) void k_mlp2(
    const float* __restrict__ t1, const float* __restrict__ Win2, const float* __restrict__ bin2,
    float* __restrict__ h)
{
    __shared__ float ts[64 * 65];
    const int tid  = threadIdx.x;
    const int w    = __builtin_amdgcn_readfirstlane(tid >> 6);
    const int lane = tid & 63;
    const int node0 = blockIdx.x * 64;
    const int cbase = blockIdx.y * 64 + w * 16;
    const int g = min(node0 + lane, NN - 1);
    const bool valid = (node0 + lane) < NN;

    for (int i = tid; i < 1024; i += 256) {
        int n = i >> 4, k4 = i & 15;
        int gr = min(node0 + n, NN - 1);
        float4 v = ((const float4*)t1)[(size_t)gr * 16 + k4];
        float* d = &ts[n * 65 + k4 * 4];
        d[0] = v.x; d[1] = v.y; d[2] = v.z; d[3] = v.w;
    }
    __syncthreads();

    float acc[16];
    #pragma unroll
    for (int i = 0; i < 16; ++i) acc[i] = 0.f;
    for (int kt = 0; kt < 8; ++kt) {
        float tv[8];
        #pragma unroll
        for (int i = 0; i < 8; ++i) tv[i] = ts[lane * 65 + kt * 8 + i];
        #pragma unroll
        for (int cc = 0; cc < 16; ++cc) {
            const float* wr = Win2 + (size_t)(cbase + cc) * MH + kt * 8;
            acc[cc] += tv[0]*wr[0] + tv[1]*wr[1] + tv[2]*wr[2] + tv[3]*wr[3]
                     + tv[4]*wr[4] + tv[5]*wr[5] + tv[6]*wr[6] + tv[7]*wr[7];
        }
    }
    if (valid) {
        float* hp = h + (size_t)g * HID + cbase;
        #pragma unroll
        for (int c4 = 0; c4 < 4; ++c4) {
            float4 v;
            v.x = acc[c4*4+0] + bin2[cbase + c4*4+0];
            v.y = acc[c4*4+1] + bin2[cbase + c4*4+1];
            v.z = acc[c4*4+2] + bin2[cbase + c4*4+2];
            v.w = acc[c4*4+3] + bin2[cbase + c4*4+3];
            *(float4*)(hp + c4 * 4) = v;
        }
    }
}

// ===========================================================================
// k_mlp3: As = h @ Wa.T, Bs = h @ Wb.T.
// v2: 16 nodes/block, ALL 128 vchannels (8/thread) -> h read ONCE (20 MB).
// grid 1250. k chunked 2x128 through LDS.
// ===========================================================================
__global__ __launch_bounds__(256) void k_mlp3(
    const float* __restrict__ h, const float* __restrict__ Wm1,
    float* __restrict__ As, float* __restrict__ Bs)
{
    __shared__ float hs[16 * 132];
    const int tid = threadIdx.x;
    const int n16 = tid >> 4;         // 0..15 node
    const int c16 = tid & 15;         // 0..15 vchannel group (8 each)
    const int node0 = blockIdx.x * 16;
    const int g = node0 + n16;
    const int which = c16 >> 3;       // 0 -> As, 1 -> Bs (uniform per thread)
    const int cb = (c16 & 7) * 8;     // channel base within 64

    float acc[8];
    #pragma unroll
    for (int i = 0; i < 8; ++i) acc[i] = 0.f;

    for (int j = 0; j < 2; ++j) {
        __syncthreads();
        for (int i = tid; i < 512; i += 256) {
            int nn = i >> 5, k4 = i & 31;
            float4 v = ((const float4*)h)[(size_t)(node0 + nn) * 64 + j * 32 + k4];
            float* d = &hs[nn * 132 + k4 * 4];
            d[0] = v.x; d[1] = v.y; d[2] = v.z; d[3] = v.w;
        }
        __syncthreads();
        for (int kt = 0; kt < 32; ++kt) {
            float x0 = hs[n16 * 132 + kt * 4 + 0];
            float x1 = hs[n16 * 132 + kt * 4 + 1];
            float x2 = hs[n16 * 132 + kt * 4 + 2];
            float x3 = hs[n16 * 132 + kt * 4 + 3];
            #pragma unroll
            for (int cc = 0; cc < 8; ++cc) {
                const float* wr = Wm1 + (size_t)(cb + cc) * (2 * HID) + which * HID
                                + j * 128 + kt * 4;
                acc[cc] += x0 * wr[0] + x1 * wr[1] + x2 * wr[2] + x3 * wr[3];
            }
        }
    }
    float* dst = (which ? Bs : As) + (size_t)g * MH + cb;
    float4 v0, v1;
    v0.x = acc[0]; v0.y = acc[1]; v0.z = acc[2]; v0.w = acc[3];
    v1.x = acc[4]; v1.y = acc[5]; v1.z = acc[6]; v1.w = acc[7];
    *(float4*)(dst + 0) = v0;
    *(float4*)(dst + 4) = v1;
}

// ===========================================================================
// k_edge_msg — 64 edges/block, chunk-rotated plds, no atomics (round 12).
// ===========================================================================
__global__ __launch_bounds__(256, 4) void k_edge_msg(
    const int* __restrict__ ei, const float* __restrict__ As, const float* __restrict__ Bs,
    const float* __restrict__ bm1, const float* __restrict__ Wm2, const float* __restrict__ bm2,
    float* __restrict__ P, float* __restrict__ Qb, float* __restrict__ Rb)
{
    __shared__ float smem[128 * 64];
    __shared__ float wm2s[16 * 68];
    const int tid = threadIdx.x;
    const int w = tid >> 6, t = tid & 63;
    const int e0 = blockIdx.x * 64;

    for (int i = tid; i < 1024; i += 256)
        wm2s[(i >> 6) * 68 + (i & 63)] = Wm2[i];

    const float bm = bm1[t];
    const int tc = t >> 2, tr = t & 3;

    for (int r = 0; r < 16; ++r) {
        const int el = w * 16 + r;
        const int e = e0 + el;
        const int src = ei[e], dst = ei[EE + e];
        float a_s = As[(size_t)src * MH + t];
        float b_d = Bs[(size_t)dst * MH + t];
        float a_d = As[(size_t)dst * MH + t];
        float b_s = Bs[(size_t)src * MH + t];
        const int row0 = el * 2, row1 = el * 2 + 1;
        smem[row0 * 64 + (((tc) + (row0 >> 2)) & 15) * 4 + tr] = fmaxf(a_s + b_d + bm, 0.f);
        smem[row1 * 64 + (((tc) + (row1 >> 2)) & 15) * 4 + tr] = fmaxf(a_d + b_s + bm, 0.f);
    }
    __syncthreads();

    float acc[4][2];
    {
        const int pg = tid & 31;
        const int jg = tid >> 5;
        const int j0 = jg * 2;
        #pragma unroll
        for (int i = 0; i < 4; ++i) { acc[i][0] = 0.f; acc[i][1] = 0.f; }

        const float4* w0 = (const float4*)&wm2s[(j0 + 0) * 68];
        const float4* w1 = (const float4*)&wm2s[(j0 + 1) * 68];
        const float4* p0 = (const float4*)&smem[(4 * pg + 0) * 64];
        const float4* p1 = (const float4*)&smem[(4 * pg + 1) * 64];
        const float4* p2 = (const float4*)&smem[(4 * pg + 2) * 64];
        const float4* p3 = (const float4*)&smem[(4 * pg + 3) * 64];

        #pragma unroll
        for (int k4 = 0; k4 < 16; ++k4) {
            const int ch = (k4 + pg) & 15;
            float4 wv0 = w0[k4], wv1 = w1[k4];
            float4 a = p0[ch], b = p1[ch], c = p2[ch], d = p3[ch];
            acc[0][0] += a.x*wv0.x + a.y*wv0.y + a.z*wv0.z + a.w*wv0.w;
            acc[0][1] += a.x*wv1.x + a.y*wv1.y + a.z*wv1.z + a.w*wv1.w;
            acc[1][0] += b.x*wv0.x + b.y*wv0.y + b.z*wv0.z + b.w*wv0.w;
            acc[1][1] += b.x*wv1.x + b.y*wv1.y + b.z*wv1.z + b.w*wv1.w;
            acc[2][0] += c.x*wv0.x + c.y*wv0.y + c.z*wv0.z + c.w*wv0.w;
            acc[2][1] += c.x*wv1.x + c.y*wv1.y + c.z*wv1.z + c.w*wv1.w;
            acc[3][0] += d.x*wv0.x + d.y*wv0.y + d.z*wv0.z + d.w*wv0.w;
            acc[3][1] += d.x*wv1.x + d.y*wv1.y + d.z*wv1.z + d.w*wv1.w;
        }
    }
    __syncthreads();

    float* fls = smem;
    {
        const int pg = tid & 31;
        const int jg = tid >> 5;
        const int j0 = jg * 2;
        float bm2a = bm2[j0], bm2b = bm2[j0 + 1];
        #pragma unroll
        for (int i = 0; i < 4; ++i) {
            fls[(4 * pg + i) * 17 + j0]     = acc[i][0] + bm2a;
            fls[(4 * pg + i) * 17 + j0 + 1] = acc[i][1] + bm2b;
        }
    }
    __syncthreads();

    {
        const int el = tid >> 2, cg = tid & 3;
        const float* f0 = &fls[(el * 2 + 0) * 17];
        const float* f1 = &fls[(el * 2 + 1) * 17];
        float a0 = f0[0*4+cg], a1 = f0[1*4+cg], a2 = f0[2*4+cg], a3 = f0[3*4+cg];
        float b0 = f1[0*4+cg], b1 = f1[1*4+cg], b2 = f1[2*4+cg], b3 = f1[3*4+cg];
        float4 pp, qq, rr;
        {
            float c0, c1, c2, c3;
            c0 = f1[0]; c1 = f1[4]; c2 = f1[8]; c3 = f1[12];
            pp.x = a0*c0 + a1*c1 + a2*c2 + a3*c3;
            rr.x = b0*c0 + b1*c1 + b2*c2 + b3*c3;
            c0 = f1[1]; c1 = f1[5]; c2 = f1[9]; c3 = f1[13];
            pp.y = a0*c0 + a1*c1 + a2*c2 + a3*c3;
            rr.y = b0*c0 + b1*c1 + b2*c2 + b3*c3;
            c0 = f1[2]; c1 = f1[6]; c2 = f1[10]; c3 = f1[14];
            pp.z = a0*c0 + a1*c1 + a2*c2 + a3*c3;
            rr.z = b0*c0 + b1*c1 + b2*c2 + b3*c3;
            c0 = f1[3]; c1 = f1[7]; c2 = f1[11]; c3 = f1[15];
            pp.w = a0*c0 + a1*c1 + a2*c2 + a3*c3;
            rr.w = b0*c0 + b1*c1 + b2*c2 + b3*c3;
            c0 = f0[0]; c1 = f0[4]; c2 = f0[8]; c3 = f0[12];
            qq.x = a0*c0 + a1*c1 + a2*c2 + a3*c3;
            c0 = f0[1]; c1 = f0[5]; c2 = f0[9]; c3 = f0[13];
            qq.y = a0*c0 + a1*c1 + a2*c2 + a3*c3;
            c0 = f0[2]; c1 = f0[6]; c2 = f0[10]; c3 = f0[14];
            qq.z = a0*c0 + a1*c1 + a2*c2 + a3*c3;
            c0 = f0[3]; c1 = f0[7]; c2 = f0[11]; c3 = f0[15];
            qq.w = a0*c0 + a1*c1 + a2*c2 + a3*c3;
        }
        const int eg = e0 + el;
        *(float4*)(P  + (size_t)eg * 16 + cg * 4) = pp;
        *(float4*)(Qb + (size_t)eg * 16 + cg * 4) = qq;
        *(float4*)(Rb + (size_t)eg * 16 + cg * 4) = rr;
    }
}

// ===========================================================================
// k_nodeM — M[n] = Σ Qb (src-inc) + Σ Rb (dst-inc) via CSR, no atomics.
// ===========================================================================
__global__ __launch_bounds__(256) void k_nodeM(
    const int* __restrict__ inc, const int* __restrict__ off,
    const float* __restrict__ Qb, const float* __restrict__ Rb,
    float* __restrict__ M)
{
    const int tid = threadIdx.x;
    const int ni = tid >> 4, comp = tid & 15;
    const int n = blockIdx.x * 16 + ni;
    const int p0 = off[n], p1 = off[n + 1];
    float s = 0.f;
    for (int p = p0; p < p1; ++p) {
        int v = inc[p];
        const float* src = (v & 1) ? Rb : Qb;
        s += src[(size_t)(v >> 1) * 16 + comp];
    }
    M[(size_t)n * 16 + comp] = s;
}

// ===========================================================================
// k_node_H — H0 = (Wd1.T @ xb) @ Wd2.T per node, stored as BF16 (packed
// per-lane layout H[n][t*4+k]). Wd2 read directly from global (L2-resident
// broadcast); no wt LDS, no barriers (tl[w] is wave-private).
// ===========================================================================
__global__ __launch_bounds__(256) void k_node_H(
    const float* __restrict__ xb,
    const float* __restrict__ Wd1l, const float* __restrict__ Wd2l,
    unsigned short* __restrict__ H)
{
    __shared__ float tl[4][4][64];
    const int tid = threadIdx.x;
    const int w = __builtin_amdgcn_readfirstlane(tid >> 6);
    const int t = tid & 63;

    float wd1[16];
    #pragma unroll
    for (int i = 0; i < 16; ++i) wd1[i] = Wd1l[i];
    const float* wrow = Wd2l + t * 64;

    for (int rep = 0; rep < 4; ++rep) {
        const int n = blockIdx.x * 16 + w * 4 + rep;
        float xv[4];
        #pragma unroll
        for (int j = 0; j < 4; ++j) xv[j] = xb[(size_t)n * HID + j * 64 + t];
        #pragma unroll
        for (int i = 0; i < 4; ++i)
            tl[w][i][t] = wd1[0 + i] * xv[0] + wd1[4 + i] * xv[1] +
                          wd1[8 + i] * xv[2] + wd1[12 + i] * xv[3];
        float a0 = 0, a1 = 0, a2 = 0, a3 = 0;
        #pragma unroll
        for (int f = 0; f < 64; f += 4) {
            float4 wv = *(const float4*)(wrow + f);
            float4 t0 = *(const float4*)&tl[w][0][f];
            float4 t1 = *(const float4*)&tl[w][1][f];
            float4 t2 = *(const float4*)&tl[w][2][f];
            float4 t3 = *(const float4*)&tl[w][3][f];
            a0 += t0.x * wv.x + t0.y * wv.y + t0.z * wv.z + t0.w * wv.w;
            a1 += t1.x * wv.x + t1.y * wv.y + t1.z * wv.z + t1.w * wv.w;
            a2 += t2.x * wv.x + t2.y * wv.y + t2.z * wv.z + t2.w * wv.w;
            a3 += t3.x * wv.x + t3.y * wv.y + t3.z * wv.z + t3.w * wv.w;
        }
        unsigned lo = (unsigned)f2bf(a0) | ((unsigned)f2bf(a1) << 16);
        unsigned hi = (unsigned)f2bf(a2) | ((unsigned)f2bf(a3) << 16);
        *(uint2*)(H + (size_t)n * HID + (t << 2)) = make_uint2(lo, hi);
    }
}

// ===========================================================================
// sheaf gather — round-2 instruction style (wave-uniform scalar index/P
// loads, packed-bf16 H), QUAD unroll: 4 H-loads + 4 P-loads in flight per
// iteration. Tails: pair + single.
// ===========================================================================
__device__ __forceinline__ void sheaf_apply(int v, uint2 u, const float pe[16], float acc[4])
{
    const float h0 = __uint_as_float(u.x << 16);
    const float h1 = __uint_as_float(u.x & 0xFFFF0000u);
    const float h2 = __uint_as_float(u.y << 16);
    const float h3 = __uint_as_float(u.y & 0xFFFF0000u);
    if (!(v & 1)) {
        #pragma unroll
        for (int j = 0; j < 4; ++j)
            acc[j] -= pe[j*4+0]*h0 + pe[j*4+1]*h1 + pe[j*4+2]*h2 + pe[j*4+3]*h3;
    } else {
        #pragma unroll
        for (int j = 0; j < 4; ++j)
            acc[j] -= pe[0*4+j]*h0 + pe[1*4+j]*h1 + pe[2*4+j]*h2 + pe[3*4+j]*h3;
    }
}

__device__ __forceinline__ void sheaf_gather(
    const int* __restrict__ inc, const int* __restrict__ inc2,
    const float* __restrict__ P, const unsigned short* __restrict__ Hin,
    int p0, int p1, int t, float acc[4])
{
    int p = p0;
    for (; p + 4 <= p1; p += 4) {
        const int vA = __builtin_amdgcn_readfirstlane(inc[p]);
        const int oA = __builtin_amdgcn_readfirstlane(inc2[p]);
        const int vB = __builtin_amdgcn_readfirstlane(inc[p + 1]);
        const int oB = __builtin_amdgcn_readfirstlane(inc2[p + 1]);
        const int vC = __builtin_amdgcn_readfirstlane(inc[p + 2]);
        const int oC = __builtin_amdgcn_readfirstlane(inc2[p + 2]);
        const int vD = __builtin_amdgcn_readfirstlane(inc[p + 3]);
        const int oD = __builtin_amdgcn_readfirstlane(inc2[p + 3]);
        const uint2 uA = *(const uint2*)(Hin + (size_t)oA * HID + (t << 2));
        const uint2 uB = *(const uint2*)(Hin + (size_t)oB * HID + (t << 2));
        const uint2 uC = *(const uint2*)(Hin + (size_t)oC * HID + (t << 2));
        const uint2 uD = *(const uint2*)(Hin + (size_t)oD * HID + (t << 2));
        const float* PA = P + (size_t)(vA >> 1) * 16;
        const float* PB = P + (size_t)(vB >> 1) * 16;
        const float* PC = P + (size_t)(vC >> 1) * 16;
        const float* PD = P + (size_t)(vD >> 1) * 16;
        float pa[16], pb[16], pc[16], pd[16];
        #pragma unroll
        for (int i = 0; i < 16; ++i) pa[i] = PA[i];
        #pragma unroll
        for (int i = 0; i < 16; ++i) pb[i] = PB[i];
        #pragma unroll
        for (int i = 0; i < 16; ++i) pc[i] = PC[i];
        #pragma unroll
        for (int i = 0; i < 16; ++i) pd[i] = PD[i];
        sheaf_apply(vA, uA, pa, acc);
        sheaf_apply(vB, uB, pb, acc);
        sheaf_apply(vC, uC, pc, acc);
        sheaf_apply(vD, uD, pd, acc);
    }
    for (; p + 2 <= p1; p += 2) {
        const int vA = __builtin_amdgcn_readfirstlane(inc[p]);
        const int oA = __builtin_amdgcn_readfirstlane(inc2[p]);
        const int vB = __builtin_amdgcn_readfirstlane(inc[p + 1]);
        const int oB = __builtin_amdgcn_readfirstlane(inc2[p + 1]);
        const uint2 uA = *(const uint2*)(Hin + (size_t)oA * HID + (t << 2));
        const uint2 uB = *(const uint2*)(Hin + (size_t)oB * HID + (t << 2));
        const float* PA = P + (size_t)(vA >> 1) * 16;
        const float* PB = P + (size_t)(vB >> 1) * 16;
        float pa[16], pb[16];
        #pragma unroll
        for (int i = 0; i < 16; ++i) pa[i] = PA[i];
        #pragma unroll
        for (int i = 0; i < 16; ++i) pb[i] = PB[i];
        sheaf_apply(vA, uA, pa, acc);
        sheaf_apply(vB, uB, pb, acc);
    }
    if (p < p1) {
        const int v = __builtin_amdgcn_readfirstlane(inc[p]);
        const int o = __builtin_amdgcn_readfirstlane(inc2[p]);
        const uint2 u = *(const uint2*)(Hin + (size_t)o * HID + (t << 2));
        const float* Pe = P + (size_t)(v >> 1) * 16;
        float pe[16];
        #pragma unroll
        for (int i = 0; i < 16; ++i) pe[i] = Pe[i];
        sheaf_apply(v, u, pe, acc);
    }
}

// ===========================================================================
// k_sheaf0 — layer 0: LH gather + xb update + fused next-layer H (bf16 out).
// Wd2 from global (L2-resident); LDS = tl only (4 KB); barrier-free.
// ===========================================================================
__global__ __launch_bounds__(256) void k_sheaf0(
    const int* __restrict__ inc, const int* __restrict__ inc2, const int* __restrict__ off,
    const float* __restrict__ P, const float* __restrict__ M,
    const unsigned short* __restrict__ Hin, float* __restrict__ h,
    unsigned short* __restrict__ Hout,
    const float* __restrict__ Wd1l, const float* __restrict__ Wd2l)
{
    __shared__ float tl[4][4][64];
    const int tid = threadIdx.x;
    const int w = __builtin_amdgcn_readfirstlane(tid >> 6);
    const int t = tid & 63;

    float wd1[16];
    #pragma unroll
    for (int i = 0; i < 16; ++i) wd1[i] = Wd1l[i];

    const int n = blockIdx.x * 4 + w;
    const uint2 un = *(const uint2*)(Hin + (size_t)n * HID + (t << 2));
    float Hn[4];
    Hn[0] = __uint_as_float(un.x << 16);
    Hn[1] = __uint_as_float(un.x & 0xFFFF0000u);
    Hn[2] = __uint_as_float(un.y << 16);
    Hn[3] = __uint_as_float(un.y & 0xFFFF0000u);
    float Mn[16];
    #pragma unroll
    for (int c = 0; c < 16; ++c) Mn[c] = M[(size_t)n * 16 + c];

    float acc[4];
    #pragma unroll
    for (int j = 0; j < 4; ++j)
        acc[j] = Mn[j*4+0]*Hn[0] + Mn[j*4+1]*Hn[1] + Mn[j*4+2]*Hn[2] + Mn[j*4+3]*Hn[3];

    const int p0 = __builtin_amdgcn_readfirstlane(off[n]);
    const int p1 = __builtin_amdgcn_readfirstlane(off[n + 1]);
    sheaf_gather(inc, inc2, P, Hin, p0, p1, t, acc);

    float xv[4];
    #pragma unroll
    for (int j = 0; j < 4; ++j) {
        size_t idx = (size_t)n * HID + j * 64 + t;
        float vv = h[idx] - fmaxf(acc[j], 0.f);
        h[idx] = vv;
        xv[j] = vv;
    }

    #pragma unroll
    for (int i = 0; i < 4; ++i)
        tl[w][i][t] = wd1[0 + i] * xv[0] + wd1[4 + i] * xv[1] +
                      wd1[8 + i] * xv[2] + wd1[12 + i] * xv[3];
    // no __syncthreads(): tl[w] is wave-private; DS ops complete in order.
    const float* wrow = Wd2l + t * 64;
    float a0 = 0, a1 = 0, a2 = 0, a3 = 0;
    #pragma unroll
    for (int f = 0; f < 64; f += 4) {
        float4 wv = *(const float4*)(wrow + f);
        float4 t0 = *(const float4*)&tl[w][0][f];
        float4 t1 = *(const float4*)&tl[w][1][f];
        float4 t2 = *(const float4*)&tl[w][2][f];
        float4 t3 = *(const float4*)&tl[w][3][f];
        a0 += t0.x * wv.x + t0.y * wv.y + t0.z * wv.z + t0.w * wv.w;
        a1 += t1.x * wv.x + t1.y * wv.y + t1.z * wv.z + t1.w * wv.w;
        a2 += t2.x * wv.x + t2.y * wv.y + t2.z * wv.z + t2.w * wv.w;
        a3 += t3.x * wv.x + t3.y * wv.y + t3.z * wv.z + t3.w * wv.w;
    }
    unsigned lo = (unsigned)f2bf(a0) | ((unsigned)f2bf(a1) << 16);
    unsigned hi = (unsigned)f2bf(a2) | ((unsigned)f2bf(a3) << 16);
    *(uint2*)(Hout + (size_t)n * HID + (t << 2)) = make_uint2(lo, hi);
}

// ===========================================================================
// k_sheaf1 — layer 1: LH gather + xb update only. ZERO LDS.
// ===========================================================================
__global__ __launch_bounds__(256) void k_sheaf1(
    const int* __restrict__ inc, const int* __restrict__ inc2, const int* __restrict__ off,
    const float* __restrict__ P, const float* __restrict__ M,
    const unsigned short* __restrict__ Hin, float* __restrict__ h)
{
    const int tid = threadIdx.x;
    const int w = __builtin_amdgcn_readfirstlane(tid >> 6);
    const int t = tid & 63;
    const int n = blockIdx.x * 4 + w;

    const uint2 un = *(const uint2*)(Hin + (size_t)n * HID + (t << 2));
    float Hn[4];
    Hn[0] = __uint_as_float(un.x << 16);
    Hn[1] = __uint_as_float(un.x & 0xFFFF0000u);
    Hn[2] = __uint_as_float(un.y << 16);
    Hn[3] = __uint_as_float(un.y & 0xFFFF0000u);
    float Mn[16];
    #pragma unroll
    for (int c = 0; c < 16; ++c) Mn[c] = M[(size_t)n * 16 + c];

    float acc[4];
    #pragma unroll
    for (int j = 0; j < 4; ++j)
        acc[j] = Mn[j*4+0]*Hn[0] + Mn[j*4+1]*Hn[1] + Mn[j*4+2]*Hn[2] + Mn[j*4+3]*Hn[3];

    const int p0 = __builtin_amdgcn_readfirstlane(off[n]);
    const int p1 = __builtin_amdgcn_readfirstlane(off[n + 1]);
    sheaf_gather(inc, inc2, P, Hin, p0, p1, t, acc);

    #pragma unroll
    for (int j = 0; j < 4; ++j) {
        size_t idx = (size_t)n * HID + j * 64 + t;
        h[idx] = h[idx] - fmaxf(acc[j], 0.f);
    }
}

// ===========================================================================
// k_out1: t1o = relu(xb @ Wo1.T + bo1).
// v2: 32 nodes/block, ALL 64 channels (8/thread) -> h read ONCE (20 MB).
// grid 625. k chunked 2x128 through LDS.
// ===========================================================================
__global__ __launch_bounds__(256) void k_out1(
    const float* __restrict__ xb, const float* __restrict__ Wo1, const float* __restrict__ bo1,
    float* __restrict__ t1o)
{
    __shared__ float xs[32 * 132];
    const int tid = threadIdx.x;
    const int n  = tid >> 3;
    const int c8 = tid & 7;
    const int node0 = blockIdx.x * 32;
    const int g = node0 + n;

    float acc[8];
    #pragma unroll
    for (int i = 0; i < 8; ++i) acc[i] = 0.f;

    for (int j = 0; j < 2; ++j) {
        __syncthreads();
        for (int i = tid; i < 1024; i += 256) {
            int nn = i >> 5, k4 = i & 31;
            float4 v = ((const float4*)xb)[(size_t)(node0 + nn) * 64 + j * 32 + k4];
            float* d = &xs[nn * 132 + k4 * 4];
            d[0] = v.x; d[1] = v.y; d[2] = v.z; d[3] = v.w;
        }
        __syncthreads();
        for (int kt = 0; kt < 32; ++kt) {
            float x0 = xs[n * 132 + kt * 4 + 0];
            float x1 = xs[n * 132 + kt * 4 + 1];
            float x2 = xs[n * 132 + kt * 4 + 2];
            float x3 = xs[n * 132 + kt * 4 + 3];
            #pragma unroll
            for (int cc = 0; cc < 8; ++cc) {
                const float* wr = Wo1 + (size_t)(c8 * 8 + cc) * HID + j * 128 + kt * 4;
                acc[cc] += x0 * wr[0] + x1 * wr[1] + x2 * wr[2] + x3 * wr[3];
            }
        }
    }
    float* dst = t1o + (size_t)g * MH + c8 * 8;
    #pragma unroll
    for (int q = 0; q < 2; ++q) {
        float4 v;
        v.x = fmaxf(acc[q*4+0] + bo1[c8*8 + q*4+0], 0.f);
        v.y = fmaxf(acc[q*4+1] + bo1[c8*8 + q*4+1], 0.f);
        v.z = fmaxf(acc[q*4+2] + bo1[c8*8 + q*4+2], 0.f);
        v.w = fmaxf(acc[q*4+3] + bo1[c8*8 + q*4+3], 0.f);
        *(float4*)(dst + q * 4) = v;
    }
}

// ===========================================================================
// k_out2: out = t1o @ Wo2.T + bo2.  (unchanged)
// ===========================================================================
__global__ __launch_bounds__(256, 4) void k_out2(
    const float* __restrict__ t1o, const float* __restrict__ Wo2, const float* __restrict__ bo2,
    float* __restrict__ out)
{
    __shared__ float ts[64 * 65];
    const int tid  = threadIdx.x;
    const int lane = tid & 63;
    const int node0 = blockIdx.x * 64;
    const int g = min(node0 + lane, NN - 1);
    const bool valid = (node0 + lane) < NN;

    for (int i = tid; i < 1024; i += 256) {
        int n = i >> 4, k4 = i & 15;
        int gr = min(node0 + n, NN - 1);
        float4 v = ((const float4*)t1o)[(size_t)gr * 16 + k4];
        float* d = &ts[n * 65 + k4 * 4];
        d[0] = v.x; d[1] = v.y; d[2] = v.z; d[3] = v.w;
    }
    __syncthreads();

    float acc[16];
    #pragma unroll
    for (int i = 0; i < 16; ++i) acc[i] = 0.f;
    for (int kt = 0; kt < 8; ++kt) {
        float tv[8];
        #pragma unroll
        for (int i = 0; i < 8; ++i) tv[i] = ts[lane * 65 + kt * 8 + i];
        #pragma unroll
        for (int jj = 0; jj < 16; ++jj) {
            const float* wr = Wo2 + (size_t)jj * MH + kt * 8;
            acc[jj] += tv[0]*wr[0] + tv[1]*wr[1] + tv[2]*wr[2] + tv[3]*wr[3]
                     + tv[4]*wr[4] + tv[5]*wr[5] + tv[6]*wr[6] + tv[7]*wr[7];
        }
    }
    if (valid) {
        float* op = out + (size_t)g * OUT_D;
        #pragma unroll
        for (int c4 = 0; c4 < 4; ++c4) {
            float4 v;
            v.x = acc[c4*4+0] + bo2[c4*4+0];
            v.y = acc[c4*4+1] + bo2[c4*4+1];
            v.z = acc[c4*4+2] + bo2[c4*4+2];
            v.w = acc[c4*4+3] + bo2[c4*4+3];
            *(float4*)(op + c4 * 4) = v;
        }
    }
}

// ---------------------------------------------------------------------------
// Workspace (~89.2 MB). Regions keep f32 sizes; H0/H1 store bf16 in the
// first half of their regions. Aliases: t1=H0, t1o=H1, Qb=H0, Rb=H1.
// Scan block-sums live in H1 (dead during CSR build).
// ---------------------------------------------------------------------------
extern "C" void kernel_launch(void* const* d_in, const int* in_sizes, int n_in,
                              void* d_out, int out_size, void* d_ws, size_t ws_size,
                              hipStream_t stream)
{
    const float* x    = (const float*)d_in[0];
    const int*   ei   = (const int*)d_in[1];
    const float* Win1 = (const float*)d_in[2];
    const float* bin1 = (const float*)d_in[3];
    const float* Win2 = (const float*)d_in[4];
    const float* bin2 = (const float*)d_in[5];
    const float* Wm1  = (const float*)d_in[6];
    const float* bm1  = (const float*)d_in[7];
    const float* Wm2  = (const float*)d_in[8];
    const float* bm2  = (const float*)d_in[9];
    const float* Wd1  = (const float*)d_in[10];
    const float* Wd2  = (const float*)d_in[11];
    const float* Wo1  = (const float*)d_in[12];
    const float* bo1  = (const float*)d_in[13];
    const float* Wo2  = (const float*)d_in[14];
    const float* bo2  = (const float*)d_in[15];
    float* out = (float*)d_out;

    float* ws = (float*)d_ws;
    float* h  = ws;                            // N*256
    float* As = h  + (size_t)NN * HID;         // N*64
    float* Bs = As + (size_t)NN * MH;          // N*64
    float* H0 = Bs + (size_t)NN * MH;          // N*256 region
    float* H1 = H0 + (size_t)NN * HID;         // N*256 region
    float* P  = H1 + (size_t)NN * HID;         // E*16
    float* M  = P  + (size_t)EE * 16;          // N*16
    int* deg    = (int*)(M + (size_t)NN * 16); // N
    int* off    = deg + NN;                    // N+1
    int* cursor = off + NN + 1;                // N
    int* inc    = cursor + NN;                 // 2E
    int* inc2   = inc + 2 * EE;                // 2E
    float* t1  = H0;                           // alias
    float* t1o = H1;                           // alias
    float* Qb  = H0;                           // alias
    float* Rb  = H1;                           // alias
    unsigned short* H0b = (unsigned short*)H0; // bf16 view (first half)
    unsigned short* H1b = (unsigned short*)H1;
    int* bsum = (int*)H1;                      // 250 ints, dead region at scan time

    const int NB = (NN + 63) / 64;             // 313

    // CSR build (parallel scan: 250x80 local -> 1-block top -> add base)
    hipMemsetAsync(deg, 0, NN * sizeof(int), stream);
    k_deg<<<(EE + 255) / 256, 256, 0, stream>>>(ei, deg);
    k_scan_a<<<250, 128, 0, stream>>>(deg, off, bsum);
    k_scan_b<<<1, 256, 0, stream>>>(bsum);
    k_scan_c<<<(NN + 255) / 256, 256, 0, stream>>>(bsum, off, cursor);
    k_scatter<<<(EE + 255) / 256, 256, 0, stream>>>(ei, cursor, inc, inc2);

    // node MLP + per-edge P/Q/R (no atomics) + CSR-gathered M
    k_mlp1<<<NN / 32, 256, 0, stream>>>(x, Win1, bin1, t1);
    k_mlp2<<<dim3(NB, 4), 256, 0, stream>>>(t1, Win2, bin2, h);
    k_mlp3<<<NN / 16, 256, 0, stream>>>(h, Wm1, As, Bs);
    k_edge_msg<<<EE / 64, 256, 0, stream>>>(ei, As, Bs, bm1, Wm2, bm2, P, Qb, Rb);
    k_nodeM<<<NN / 16, 256, 0, stream>>>(inc, off, Qb, Rb, M);

    // diffusion (H in bf16, packed per-lane layout)
    k_node_H<<<NN / 16, 256, 0, stream>>>(h, Wd1, Wd2, H0b);
    k_sheaf0<<<NN / 4, 256, 0, stream>>>(inc, inc2, off, P, M, H0b, h, H1b,
                                         Wd1 + 16, Wd2 + 4096);
    k_sheaf1<<<NN / 4, 256, 0, stream>>>(inc, inc2, off, P, M, H1b, h);

    // output MLP
    k_out1<<<NN / 32, 256, 0, stream>>>(h, Wo1, bo1, t1o);
    k_out2<<<NB, 256, 0, stream>>>(t1o, Wo2, bo2, out);
}

// Round 6
// 486.070 us; speedup vs baseline: 2.3904x; 2.3904x over previous
//
#include <hip/hip_runtime.h>

constexpr int NN   = 20000;
constexpr int EE   = 200000;
constexpr int IN_D = 500;
constexpr int HID  = 256;
constexpr int OUT_D= 16;
constexpr int MH   = 64;

// bf16 helpers (internal H storage only)
__device__ __forceinline__ float bf2f(unsigned short s) {
    return __uint_as_float((unsigned)s << 16);
}
__device__ __forceinline__ unsigned short f2bf(float f) {
    unsigned u = __float_as_uint(f);
    unsigned r = u + 0x7FFF + ((u >> 16) & 1);   // round-to-nearest-even
    return (unsigned short)(r >> 16);
}

// ===========================================================================
// CSR incidence build. inc entry = edge*2 + is_dst; inc2 entry = other node.
// ===========================================================================
__global__ __launch_bounds__(256) void k_deg(const int* __restrict__ ei, int* __restrict__ deg)
{
    int e = blockIdx.x * 256 + threadIdx.x;
    if (e < EE) {
        atomicAdd(deg + ei[e], 1);
        atomicAdd(deg + ei[EE + e], 1);
    }
}

// Parallel scan, 3 kernels. Block sums parked in dead H1 region.
__global__ __launch_bounds__(128) void k_scan_a(const int* __restrict__ deg,
                                                int* __restrict__ off, int* __restrict__ bsum)
{
    __shared__ int s[128];
    const int b = blockIdx.x, tid = threadIdx.x;
    const int n = b * 80 + tid;
    int v = (tid < 80) ? deg[n] : 0;
    s[tid] = v;
    __syncthreads();
    for (int o = 1; o < 128; o <<= 1) {
        int x = 0;
        if (tid >= o) x = s[tid - o];
        __syncthreads();
        if (tid >= o) s[tid] += x;
        __syncthreads();
    }
    if (tid < 80) off[n] = s[tid] - v;     // local exclusive prefix
    if (tid == 127) bsum[b] = s[127];      // block total
}

__global__ __launch_bounds__(256) void k_scan_b(int* __restrict__ bsum)
{
    __shared__ int s[256];
    const int tid = threadIdx.x;
    int v = (tid < 250) ? bsum[tid] : 0;
    s[tid] = v;
    __syncthreads();
    for (int o = 1; o < 256; o <<= 1) {
        int x = 0;
        if (tid >= o) x = s[tid - o];
        __syncthreads();
        if (tid >= o) s[tid] += x;
        __syncthreads();
    }
    if (tid < 250) bsum[tid] = s[tid] - v; // exclusive
}

__global__ __launch_bounds__(256) void k_scan_c(const int* __restrict__ bsum,
                                                int* __restrict__ off, int* __restrict__ cursor)
{
    const int n = blockIdx.x * 256 + threadIdx.x;
    if (n < NN) {
        int o = off[n] + bsum[n / 80];
        off[n] = o;
        cursor[n] = o;
    }
    if (n == 0) off[NN] = 2 * EE;
}

__global__ __launch_bounds__(256) void k_scatter(const int* __restrict__ ei,
                                                 int* __restrict__ cursor,
                                                 int* __restrict__ inc, int* __restrict__ inc2)
{
    int e = blockIdx.x * 256 + threadIdx.x;
    if (e < EE) {
        int s = ei[e], d = ei[EE + e];
        int p = atomicAdd(cursor + s, 1); inc[p] = e * 2;     inc2[p] = d;
        p = atomicAdd(cursor + d, 1);     inc[p] = e * 2 + 1; inc2[p] = s;
    }
}

// ===========================================================================
// k_mlp1: t1 = relu(x @ Win1.T + bin1).  grid (N/64, 4).
// Wave-uniform weight rows -> scalar-pipe weight loads. (Round-4 verbatim;
// round-5's input-reuse restructure regressed 5x: L3 already absorbed the
// re-reads, and per-lane weight rows turned s_loads into latency-chained
// vector loads.)
// ===========================================================================
__global__ __launch_bounds__(256, 4) void k_mlp1(
    const float* __restrict__ x, const float* __restrict__ Win1, const float* __restrict__ bin1,
    float* __restrict__ t1)
{
    __shared__ float xs[64 * 101];
    const int tid  = threadIdx.x;
    const int w    = __builtin_amdgcn_readfirstlane(tid >> 6);
    const int lane = tid & 63;
    const int node0 = blockIdx.x * 64;
    const int cbase = blockIdx.y * 16 + w * 4;
    const int g = min(node0 + lane, NN - 1);
    const bool valid = (node0 + lane) < NN;

    float acc[4] = {0.f, 0.f, 0.f, 0.f};

    for (int j = 0; j < 5; ++j) {
        __syncthreads();
        for (int i = tid; i < 1600; i += 256) {
            int n = i / 25, k4 = i % 25;
            int gr = min(node0 + n, NN - 1);
            float4 v = ((const float4*)x)[(size_t)gr * 125 + j * 25 + k4];
            float* d = &xs[n * 101 + k4 * 4];
            d[0] = v.x; d[1] = v.y; d[2] = v.z; d[3] = v.w;
        }
        __syncthreads();
        for (int kt = 0; kt < 25; ++kt) {
            float x0 = xs[lane * 101 + kt * 4 + 0];
            float x1 = xs[lane * 101 + kt * 4 + 1];
            float x2 = xs[lane * 101 + kt * 4 + 2];
            float x3 = xs[lane * 101 + kt * 4 + 3];
            #pragma unroll
            for (int cc = 0; cc < 4; ++cc) {
                const float* wr = Win1 + (size_t)(cbase + cc) * IN_D + j * 100 + kt * 4;
                acc[cc] += x0 * wr[0] + x1 * wr[1] + x2 * wr[2] + x3 * wr[3];
            }
        }
    }
    if (valid) {
        float4 v;
        v.x = fmaxf(acc[0] + bin1[cbase + 0], 0.f);
        v.y = fmaxf(acc[1] + bin1[cbase + 1], 0.f);
        v.z = fmaxf(acc[2] + bin1[cbase + 2], 0.f);
        v.w = fmaxf(acc[3] + bin1[cbase + 3], 0.f);
        *(float4*)(t1 + (size_t)g * MH + cbase) = v;
    }
}

// ===========================================================================
// k_mlp2: h = t1 @ Win2.T + bin2.  grid (N/64, 4).
// ===========================================================================
__global__ __launch_bounds__(256, 4) void k_mlp2(
    const float* __restrict__ t1, const float* __restrict__ Win2, const float* __restrict__ bin2,
    float* __restrict__ h)
{
    __shared__ float ts[64 * 65];
    const int tid  = threadIdx.x;
    const int w    = __builtin_amdgcn_readfirstlane(tid >> 6);
    const int lane = tid & 63;
    const int node0 = blockIdx.x * 64;
    const int cbase = blockIdx.y * 64 + w * 16;
    const int g = min(node0 + lane, NN - 1);
    const bool valid = (node0 + lane) < NN;

    for (int i = tid; i < 1024; i += 256) {
        int n = i >> 4, k4 = i & 15;
        int gr = min(node0 + n, NN - 1);
        float4 v = ((const float4*)t1)[(size_t)gr * 16 + k4];
        float* d = &ts[n * 65 + k4 * 4];
        d[0] = v.x; d[1] = v.y; d[2] = v.z; d[3] = v.w;
    }
    __syncthreads();

    float acc[16];
    #pragma unroll
    for (int i = 0; i < 16; ++i) acc[i] = 0.f;
    for (int kt = 0; kt < 8; ++kt) {
        float tv[8];
        #pragma unroll
        for (int i = 0; i < 8; ++i) tv[i] = ts[lane * 65 + kt * 8 + i];
        #pragma unroll
        for (int cc = 0; cc < 16; ++cc) {
            const float* wr = Win2 + (size_t)(cbase + cc) * MH + kt * 8;
            acc[cc] += tv[0]*wr[0] + tv[1]*wr[1] + tv[2]*wr[2] + tv[3]*wr[3]
                     + tv[4]*wr[4] + tv[5]*wr[5] + tv[6]*wr[6] + tv[7]*wr[7];
        }
    }
    if (valid) {
        float* hp = h + (size_t)g * HID + cbase;
        #pragma unroll
        for (int c4 = 0; c4 < 4; ++c4) {
            float4 v;
            v.x = acc[c4*4+0] + bin2[cbase + c4*4+0];
            v.y = acc[c4*4+1] + bin2[cbase + c4*4+1];
            v.z = acc[c4*4+2] + bin2[cbase + c4*4+2];
            v.w = acc[c4*4+3] + bin2[cbase + c4*4+3];
            *(float4*)(hp + c4 * 4) = v;
        }
    }
}

// ===========================================================================
// k_mlp3: As = h @ Wa.T, Bs = h @ Wb.T.  grid (N/64, 4).  (round-4 verbatim)
// ===========================================================================
__global__ __launch_bounds__(256, 4) void k_mlp3(
    const float* __restrict__ h, const float* __restrict__ Wm1,
    float* __restrict__ As, float* __restrict__ Bs)
{
    __shared__ float hsm[64 * 65];
    const int tid  = threadIdx.x;
    const int w    = __builtin_amdgcn_readfirstlane(tid >> 6);
    const int lane = tid & 63;
    const int node0 = blockIdx.x * 64;
    const int vcb = blockIdx.y * 32 + w * 8;
    const int which = vcb >> 6;
    const int cb = vcb & 63;
    const int g = min(node0 + lane, NN - 1);
    const bool valid = (node0 + lane) < NN;

    float acc[8];
    #pragma unroll
    for (int i = 0; i < 8; ++i) acc[i] = 0.f;

    for (int ch = 0; ch < 4; ++ch) {
        __syncthreads();
        for (int i = tid; i < 1024; i += 256) {
            int n = i >> 4, k4 = i & 15;
            int gr = min(node0 + n, NN - 1);
            float4 v = ((const float4*)h)[(size_t)gr * 64 + ch * 16 + k4];
            float* d = &hsm[n * 65 + k4 * 4];
            d[0] = v.x; d[1] = v.y; d[2] = v.z; d[3] = v.w;
        }
        __syncthreads();
        for (int kt = 0; kt < 8; ++kt) {
            float tv[8];
            #pragma unroll
            for (int i = 0; i < 8; ++i) tv[i] = hsm[lane * 65 + kt * 8 + i];
            #pragma unroll
            for (int jj = 0; jj < 8; ++jj) {
                const float* wr = Wm1 + (size_t)(cb + jj) * (2 * HID) + which * HID
                                + ch * 64 + kt * 8;
                acc[jj] += tv[0]*wr[0] + tv[1]*wr[1] + tv[2]*wr[2] + tv[3]*wr[3]
                         + tv[4]*wr[4] + tv[5]*wr[5] + tv[6]*wr[6] + tv[7]*wr[7];
            }
        }
    }
    if (valid) {
        float* dst = (which ? Bs : As) + (size_t)g * MH + cb;
        float4 v0, v1;
        v0.x = acc[0]; v0.y = acc[1]; v0.z = acc[2]; v0.w = acc[3];
        v1.x = acc[4]; v1.y = acc[5]; v1.z = acc[6]; v1.w = acc[7];
        *(float4*)(dst + 0) = v0;
        *(float4*)(dst + 4) = v1;
    }
}

// ===========================================================================
// k_edge_msg — 64 edges/block, chunk-rotated plds, no atomics (round 12).
// ===========================================================================
__global__ __launch_bounds__(256, 4) void k_edge_msg(
    const int* __restrict__ ei, const float* __restrict__ As, const float* __restrict__ Bs,
    const float* __restrict__ bm1, const float* __restrict__ Wm2, const float* __restrict__ bm2,
    float* __restrict__ P, float* __restrict__ Qb, float* __restrict__ Rb)
{
    __shared__ float smem[128 * 64];
    __shared__ float wm2s[16 * 68];
    const int tid = threadIdx.x;
    const int w = tid >> 6, t = tid & 63;
    const int e0 = blockIdx.x * 64;

    for (int i = tid; i < 1024; i += 256)
        wm2s[(i >> 6) * 68 + (i & 63)] = Wm2[i];

    const float bm = bm1[t];
    const int tc = t >> 2, tr = t & 3;

    for (int r = 0; r < 16; ++r) {
        const int el = w * 16 + r;
        const int e = e0 + el;
        const int src = ei[e], dst = ei[EE + e];
        float a_s = As[(size_t)src * MH + t];
        float b_d = Bs[(size_t)dst * MH + t];
        float a_d = As[(size_t)dst * MH + t];
        float b_s = Bs[(size_t)src * MH + t];
        const int row0 = el * 2, row1 = el * 2 + 1;
        smem[row0 * 64 + (((tc) + (row0 >> 2)) & 15) * 4 + tr] = fmaxf(a_s + b_d + bm, 0.f);
        smem[row1 * 64 + (((tc) + (row1 >> 2)) & 15) * 4 + tr] = fmaxf(a_d + b_s + bm, 0.f);
    }
    __syncthreads();

    float acc[4][2];
    {
        const int pg = tid & 31;
        const int jg = tid >> 5;
        const int j0 = jg * 2;
        #pragma unroll
        for (int i = 0; i < 4; ++i) { acc[i][0] = 0.f; acc[i][1] = 0.f; }

        const float4* w0 = (const float4*)&wm2s[(j0 + 0) * 68];
        const float4* w1 = (const float4*)&wm2s[(j0 + 1) * 68];
        const float4* p0 = (const float4*)&smem[(4 * pg + 0) * 64];
        const float4* p1 = (const float4*)&smem[(4 * pg + 1) * 64];
        const float4* p2 = (const float4*)&smem[(4 * pg + 2) * 64];
        const float4* p3 = (const float4*)&smem[(4 * pg + 3) * 64];

        #pragma unroll
        for (int k4 = 0; k4 < 16; ++k4) {
            const int ch = (k4 + pg) & 15;
            float4 wv0 = w0[k4], wv1 = w1[k4];
            float4 a = p0[ch], b = p1[ch], c = p2[ch], d = p3[ch];
            acc[0][0] += a.x*wv0.x + a.y*wv0.y + a.z*wv0.z + a.w*wv0.w;
            acc[0][1] += a.x*wv1.x + a.y*wv1.y + a.z*wv1.z + a.w*wv1.w;
            acc[1][0] += b.x*wv0.x + b.y*wv0.y + b.z*wv0.z + b.w*wv0.w;
            acc[1][1] += b.x*wv1.x + b.y*wv1.y + b.z*wv1.z + b.w*wv1.w;
            acc[2][0] += c.x*wv0.x + c.y*wv0.y + c.z*wv0.z + c.w*wv0.w;
            acc[2][1] += c.x*wv1.x + c.y*wv1.y + c.z*wv1.z + c.w*wv1.w;
            acc[3][0] += d.x*wv0.x + d.y*wv0.y + d.z*wv0.z + d.w*wv0.w;
            acc[3][1] += d.x*wv1.x + d.y*wv1.y + d.z*wv1.z + d.w*wv1.w;
        }
    }
    __syncthreads();

    float* fls = smem;
    {
        const int pg = tid & 31;
        const int jg = tid >> 5;
        const int j0 = jg * 2;
        float bm2a = bm2[j0], bm2b = bm2[j0 + 1];
        #pragma unroll
        for (int i = 0; i < 4; ++i) {
            fls[(4 * pg + i) * 17 + j0]     = acc[i][0] + bm2a;
            fls[(4 * pg + i) * 17 + j0 + 1] = acc[i][1] + bm2b;
        }
    }
    __syncthreads();

    {
        const int el = tid >> 2, cg = tid & 3;
        const float* f0 = &fls[(el * 2 + 0) * 17];
        const float* f1 = &fls[(el * 2 + 1) * 17];
        float a0 = f0[0*4+cg], a1 = f0[1*4+cg], a2 = f0[2*4+cg], a3 = f0[3*4+cg];
        float b0 = f1[0*4+cg], b1 = f1[1*4+cg], b2 = f1[2*4+cg], b3 = f1[3*4+cg];
        float4 pp, qq, rr;
        {
            float c0, c1, c2, c3;
            c0 = f1[0]; c1 = f1[4]; c2 = f1[8]; c3 = f1[12];
            pp.x = a0*c0 + a1*c1 + a2*c2 + a3*c3;
            rr.x = b0*c0 + b1*c1 + b2*c2 + b3*c3;
            c0 = f1[1]; c1 = f1[5]; c2 = f1[9]; c3 = f1[13];
            pp.y = a0*c0 + a1*c1 + a2*c2 + a3*c3;
            rr.y = b0*c0 + b1*c1 + b2*c2 + b3*c3;
            c0 = f1[2]; c1 = f1[6]; c2 = f1[10]; c3 = f1[14];
            pp.z = a0*c0 + a1*c1 + a2*c2 + a3*c3;
            rr.z = b0*c0 + b1*c1 + b2*c2 + b3*c3;
            c0 = f1[3]; c1 = f1[7]; c2 = f1[11]; c3 = f1[15];
            pp.w = a0*c0 + a1*c1 + a2*c2 + a3*c3;
            rr.w = b0*c0 + b1*c1 + b2*c2 + b3*c3;
            c0 = f0[0]; c1 = f0[4]; c2 = f0[8]; c3 = f0[12];
            qq.x = a0*c0 + a1*c1 + a2*c2 + a3*c3;
            c0 = f0[1]; c1 = f0[5]; c2 = f0[9]; c3 = f0[13];
            qq.y = a0*c0 + a1*c1 + a2*c2 + a3*c3;
            c0 = f0[2]; c1 = f0[6]; c2 = f0[10]; c3 = f0[14];
            qq.z = a0*c0 + a1*c1 + a2*c2 + a3*c3;
            c0 = f0[3]; c1 = f0[7]; c2 = f0[11]; c3 = f0[15];
            qq.w = a0*c0 + a1*c1 + a2*c2 + a3*c3;
        }
        const int eg = e0 + el;
        *(float4*)(P  + (size_t)eg * 16 + cg * 4) = pp;
        *(float4*)(Qb + (size_t)eg * 16 + cg * 4) = qq;
        *(float4*)(Rb + (size_t)eg * 16 + cg * 4) = rr;
    }
}

// ===========================================================================
// k_nodeM — M[n] = Σ Qb (src-inc) + Σ Rb (dst-inc) via CSR, no atomics.
// ===========================================================================
__global__ __launch_bounds__(256) void k_nodeM(
    const int* __restrict__ inc, const int* __restrict__ off,
    const float* __restrict__ Qb, const float* __restrict__ Rb,
    float* __restrict__ M)
{
    const int tid = threadIdx.x;
    const int ni = tid >> 4, comp = tid & 15;
    const int n = blockIdx.x * 16 + ni;
    const int p0 = off[n], p1 = off[n + 1];
    float s = 0.f;
    for (int p = p0; p < p1; ++p) {
        int v = inc[p];
        const float* src = (v & 1) ? Rb : Qb;
        s += src[(size_t)(v >> 1) * 16 + comp];
    }
    M[(size_t)n * 16 + comp] = s;
}

// ===========================================================================
// k_node_H — H0 = (Wd1.T @ xb) @ Wd2.T per node, stored as BF16 (packed
// per-lane layout H[n][t*4+k]). Wd2 read directly from global (L2-resident
// broadcast); no wt LDS, no barriers (tl[w] is wave-private).
// ===========================================================================
__global__ __launch_bounds__(256) void k_node_H(
    const float* __restrict__ xb,
    const float* __restrict__ Wd1l, const float* __restrict__ Wd2l,
    unsigned short* __restrict__ H)
{
    __shared__ float tl[4][4][64];
    const int tid = threadIdx.x;
    const int w = __builtin_amdgcn_readfirstlane(tid >> 6);
    const int t = tid & 63;

    float wd1[16];
    #pragma unroll
    for (int i = 0; i < 16; ++i) wd1[i] = Wd1l[i];
    const float* wrow = Wd2l + t * 64;

    for (int rep = 0; rep < 4; ++rep) {
        const int n = blockIdx.x * 16 + w * 4 + rep;
        float xv[4];
        #pragma unroll
        for (int j = 0; j < 4; ++j) xv[j] = xb[(size_t)n * HID + j * 64 + t];
        #pragma unroll
        for (int i = 0; i < 4; ++i)
            tl[w][i][t] = wd1[0 + i] * xv[0] + wd1[4 + i] * xv[1] +
                          wd1[8 + i] * xv[2] + wd1[12 + i] * xv[3];
        float a0 = 0, a1 = 0, a2 = 0, a3 = 0;
        #pragma unroll
        for (int f = 0; f < 64; f += 4) {
            float4 wv = *(const float4*)(wrow + f);
            float4 t0 = *(const float4*)&tl[w][0][f];
            float4 t1 = *(const float4*)&tl[w][1][f];
            float4 t2 = *(const float4*)&tl[w][2][f];
            float4 t3 = *(const float4*)&tl[w][3][f];
            a0 += t0.x * wv.x + t0.y * wv.y + t0.z * wv.z + t0.w * wv.w;
            a1 += t1.x * wv.x + t1.y * wv.y + t1.z * wv.z + t1.w * wv.w;
            a2 += t2.x * wv.x + t2.y * wv.y + t2.z * wv.z + t2.w * wv.w;
            a3 += t3.x * wv.x + t3.y * wv.y + t3.z * wv.z + t3.w * wv.w;
        }
        unsigned lo = (unsigned)f2bf(a0) | ((unsigned)f2bf(a1) << 16);
        unsigned hi = (unsigned)f2bf(a2) | ((unsigned)f2bf(a3) << 16);
        *(uint2*)(H + (size_t)n * HID + (t << 2)) = make_uint2(lo, hi);
    }
}

// ===========================================================================
// sheaf gather — round-2 instruction style (wave-uniform scalar index/P
// loads, packed-bf16 H), QUAD unroll: 4 H-loads + 4 P-loads in flight per
// iteration. Tails: pair + single.
// ===========================================================================
__device__ __forceinline__ void sheaf_apply(int v, uint2 u, const float pe[16], float acc[4])
{
    const float h0 = __uint_as_float(u.x << 16);
    const float h1 = __uint_as_float(u.x & 0xFFFF0000u);
    const float h2 = __uint_as_float(u.y << 16);
    const float h3 = __uint_as_float(u.y & 0xFFFF0000u);
    if (!(v & 1)) {
        #pragma unroll
        for (int j = 0; j < 4; ++j)
            acc[j] -= pe[j*4+0]*h0 + pe[j*4+1]*h1 + pe[j*4+2]*h2 + pe[j*4+3]*h3;
    } else {
        #pragma unroll
        for (int j = 0; j < 4; ++j)
            acc[j] -= pe[0*4+j]*h0 + pe[1*4+j]*h1 + pe[2*4+j]*h2 + pe[3*4+j]*h3;
    }
}

__device__ __forceinline__ void sheaf_gather(
    const int* __restrict__ inc, const int* __restrict__ inc2,
    const float* __restrict__ P, const unsigned short* __restrict__ Hin,
    int p0, int p1, int t, float acc[4])
{
    int p = p0;
    for (; p + 4 <= p1; p += 4) {
        const int vA = __builtin_amdgcn_readfirstlane(inc[p]);
        const int oA = __builtin_amdgcn_readfirstlane(inc2[p]);
        const int vB = __builtin_amdgcn_readfirstlane(inc[p + 1]);
        const int oB = __builtin_amdgcn_readfirstlane(inc2[p + 1]);
        const int vC = __builtin_amdgcn_readfirstlane(inc[p + 2]);
        const int oC = __builtin_amdgcn_readfirstlane(inc2[p + 2]);
        const int vD = __builtin_amdgcn_readfirstlane(inc[p + 3]);
        const int oD = __builtin_amdgcn_readfirstlane(inc2[p + 3]);
        const uint2 uA = *(const uint2*)(Hin + (size_t)oA * HID + (t << 2));
        const uint2 uB = *(const uint2*)(Hin + (size_t)oB * HID + (t << 2));
        const uint2 uC = *(const uint2*)(Hin + (size_t)oC * HID + (t << 2));
        const uint2 uD = *(const uint2*)(Hin + (size_t)oD * HID + (t << 2));
        const float* PA = P + (size_t)(vA >> 1) * 16;
        const float* PB = P + (size_t)(vB >> 1) * 16;
        const float* PC = P + (size_t)(vC >> 1) * 16;
        const float* PD = P + (size_t)(vD >> 1) * 16;
        float pa[16], pb[16], pc[16], pd[16];
        #pragma unroll
        for (int i = 0; i < 16; ++i) pa[i] = PA[i];
        #pragma unroll
        for (int i = 0; i < 16; ++i) pb[i] = PB[i];
        #pragma unroll
        for (int i = 0; i < 16; ++i) pc[i] = PC[i];
        #pragma unroll
        for (int i = 0; i < 16; ++i) pd[i] = PD[i];
        sheaf_apply(vA, uA, pa, acc);
        sheaf_apply(vB, uB, pb, acc);
        sheaf_apply(vC, uC, pc, acc);
        sheaf_apply(vD, uD, pd, acc);
    }
    for (; p + 2 <= p1; p += 2) {
        const int vA = __builtin_amdgcn_readfirstlane(inc[p]);
        const int oA = __builtin_amdgcn_readfirstlane(inc2[p]);
        const int vB = __builtin_amdgcn_readfirstlane(inc[p + 1]);
        const int oB = __builtin_amdgcn_readfirstlane(inc2[p + 1]);
        const uint2 uA = *(const uint2*)(Hin + (size_t)oA * HID + (t << 2));
        const uint2 uB = *(const uint2*)(Hin + (size_t)oB * HID + (t << 2));
        const float* PA = P + (size_t)(vA >> 1) * 16;
        const float* PB = P + (size_t)(vB >> 1) * 16;
        float pa[16], pb[16];
        #pragma unroll
        for (int i = 0; i < 16; ++i) pa[i] = PA[i];
        #pragma unroll
        for (int i = 0; i < 16; ++i) pb[i] = PB[i];
        sheaf_apply(vA, uA, pa, acc);
        sheaf_apply(vB, uB, pb, acc);
    }
    if (p < p1) {
        const int v = __builtin_amdgcn_readfirstlane(inc[p]);
        const int o = __builtin_amdgcn_readfirstlane(inc2[p]);
        const uint2 u = *(const uint2*)(Hin + (size_t)o * HID + (t << 2));
        const float* Pe = P + (size_t)(v >> 1) * 16;
        float pe[16];
        #pragma unroll
        for (int i = 0; i < 16; ++i) pe[i] = Pe[i];
        sheaf_apply(v, u, pe, acc);
    }
}

// ===========================================================================
// k_sheaf0 — layer 0: LH gather + xb update + fused next-layer H (bf16 out).
// Wd2 from global (L2-resident); LDS = tl only (4 KB); barrier-free.
// ===========================================================================
__global__ __launch_bounds__(256) void k_sheaf0(
    const int* __restrict__ inc, const int* __restrict__ inc2, const int* __restrict__ off,
    const float* __restrict__ P, const float* __restrict__ M,
    const unsigned short* __restrict__ Hin, float* __restrict__ h,
    unsigned short* __restrict__ Hout,
    const float* __restrict__ Wd1l, const float* __restrict__ Wd2l)
{
    __shared__ float tl[4][4][64];
    const int tid = threadIdx.x;
    const int w = __builtin_amdgcn_readfirstlane(tid >> 6);
    const int t = tid & 63;

    float wd1[16];
    #pragma unroll
    for (int i = 0; i < 16; ++i) wd1[i] = Wd1l[i];

    const int n = blockIdx.x * 4 + w;
    const uint2 un = *(const uint2*)(Hin + (size_t)n * HID + (t << 2));
    float Hn[4];
    Hn[0] = __uint_as_float(un.x << 16);
    Hn[1] = __uint_as_float(un.x & 0xFFFF0000u);
    Hn[2] = __uint_as_float(un.y << 16);
    Hn[3] = __uint_as_float(un.y & 0xFFFF0000u);
    float Mn[16];
    #pragma unroll
    for (int c = 0; c < 16; ++c) Mn[c] = M[(size_t)n * 16 + c];

    float acc[4];
    #pragma unroll
    for (int j = 0; j < 4; ++j)
        acc[j] = Mn[j*4+0]*Hn[0] + Mn[j*4+1]*Hn[1] + Mn[j*4+2]*Hn[2] + Mn[j*4+3]*Hn[3];

    const int p0 = __builtin_amdgcn_readfirstlane(off[n]);
    const int p1 = __builtin_amdgcn_readfirstlane(off[n + 1]);
    sheaf_gather(inc, inc2, P, Hin, p0, p1, t, acc);

    float xv[4];
    #pragma unroll
    for (int j = 0; j < 4; ++j) {
        size_t idx = (size_t)n * HID + j * 64 + t;
        float vv = h[idx] - fmaxf(acc[j], 0.f);
        h[idx] = vv;
        xv[j] = vv;
    }

    #pragma unroll
    for (int i = 0; i < 4; ++i)
        tl[w][i][t] = wd1[0 + i] * xv[0] + wd1[4 + i] * xv[1] +
                      wd1[8 + i] * xv[2] + wd1[12 + i] * xv[3];
    // no __syncthreads(): tl[w] is wave-private; DS ops complete in order.
    const float* wrow = Wd2l + t * 64;
    float a0 = 0, a1 = 0, a2 = 0, a3 = 0;
    #pragma unroll
    for (int f = 0; f < 64; f += 4) {
        float4 wv = *(const float4*)(wrow + f);
        float4 t0 = *(const float4*)&tl[w][0][f];
        float4 t1 = *(const float4*)&tl[w][1][f];
        float4 t2 = *(const float4*)&tl[w][2][f];
        float4 t3 = *(const float4*)&tl[w][3][f];
        a0 += t0.x * wv.x + t0.y * wv.y + t0.z * wv.z + t0.w * wv.w;
        a1 += t1.x * wv.x + t1.y * wv.y + t1.z * wv.z + t1.w * wv.w;
        a2 += t2.x * wv.x + t2.y * wv.y + t2.z * wv.z + t2.w * wv.w;
        a3 += t3.x * wv.x + t3.y * wv.y + t3.z * wv.z + t3.w * wv.w;
    }
    unsigned lo = (unsigned)f2bf(a0) | ((unsigned)f2bf(a1) << 16);
    unsigned hi = (unsigned)f2bf(a2) | ((unsigned)f2bf(a3) << 16);
    *(uint2*)(Hout + (size_t)n * HID + (t << 2)) = make_uint2(lo, hi);
}

// ===========================================================================
// k_sheaf1 — layer 1: LH gather + xb update only. ZERO LDS.
// ===========================================================================
__global__ __launch_bounds__(256) void k_sheaf1(
    const int* __restrict__ inc, const int* __restrict__ inc2, const int* __restrict__ off,
    const float* __restrict__ P, const float* __restrict__ M,
    const unsigned short* __restrict__ Hin, float* __restrict__ h)
{
    const int tid = threadIdx.x;
    const int w = __builtin_amdgcn_readfirstlane(tid >> 6);
    const int t = tid & 63;
    const int n = blockIdx.x * 4 + w;

    const uint2 un = *(const uint2*)(Hin + (size_t)n * HID + (t << 2));
    float Hn[4];
    Hn[0] = __uint_as_float(un.x << 16);
    Hn[1] = __uint_as_float(un.x & 0xFFFF0000u);
    Hn[2] = __uint_as_float(un.y << 16);
    Hn[3] = __uint_as_float(un.y & 0xFFFF0000u);
    float Mn[16];
    #pragma unroll
    for (int c = 0; c < 16; ++c) Mn[c] = M[(size_t)n * 16 + c];

    float acc[4];
    #pragma unroll
    for (int j = 0; j < 4; ++j)
        acc[j] = Mn[j*4+0]*Hn[0] + Mn[j*4+1]*Hn[1] + Mn[j*4+2]*Hn[2] + Mn[j*4+3]*Hn[3];

    const int p0 = __builtin_amdgcn_readfirstlane(off[n]);
    const int p1 = __builtin_amdgcn_readfirstlane(off[n + 1]);
    sheaf_gather(inc, inc2, P, Hin, p0, p1, t, acc);

    #pragma unroll
    for (int j = 0; j < 4; ++j) {
        size_t idx = (size_t)n * HID + j * 64 + t;
        h[idx] = h[idx] - fmaxf(acc[j], 0.f);
    }
}

// ===========================================================================
// k_out1: t1o = relu(xb @ Wo1.T + bo1).  grid (N/64, 4).  (round-4 verbatim)
// ===========================================================================
__global__ __launch_bounds__(256, 4) void k_out1(
    const float* __restrict__ xb, const float* __restrict__ Wo1, const float* __restrict__ bo1,
    float* __restrict__ t1o)
{
    __shared__ float xr[64 * 129];
    const int tid  = threadIdx.x;
    const int w    = __builtin_amdgcn_readfirstlane(tid >> 6);
    const int lane = tid & 63;
    const int node0 = blockIdx.x * 64;
    const int cbase = blockIdx.y * 16 + w * 4;
    const int g = min(node0 + lane, NN - 1);
    const bool valid = (node0 + lane) < NN;

    float acc[4] = {0.f, 0.f, 0.f, 0.f};

    for (int j = 0; j < 2; ++j) {
        __syncthreads();
        for (int i = tid; i < 2048; i += 256) {
            int n = i >> 5, k4 = i & 31;
            int gr = min(node0 + n, NN - 1);
            float4 v = ((const float4*)xb)[(size_t)gr * 64 + j * 32 + k4];
            float* d = &xr[n * 129 + k4 * 4];
            d[0] = v.x; d[1] = v.y; d[2] = v.z; d[3] = v.w;
        }
        __syncthreads();
        for (int kt = 0; kt < 32; ++kt) {
            float x0 = xr[lane * 129 + kt * 4 + 0];
            float x1 = xr[lane * 129 + kt * 4 + 1];
            float x2 = xr[lane * 129 + kt * 4 + 2];
            float x3 = xr[lane * 129 + kt * 4 + 3];
            #pragma unroll
            for (int cc = 0; cc < 4; ++cc) {
                const float* wr = Wo1 + (size_t)(cbase + cc) * HID + j * 128 + kt * 4;
                acc[cc] += x0 * wr[0] + x1 * wr[1] + x2 * wr[2] + x3 * wr[3];
            }
        }
    }
    if (valid) {
        float4 v;
        v.x = fmaxf(acc[0] + bo1[cbase + 0], 0.f);
        v.y = fmaxf(acc[1] + bo1[cbase + 1], 0.f);
        v.z = fmaxf(acc[2] + bo1[cbase + 2], 0.f);
        v.w = fmaxf(acc[3] + bo1[cbase + 3], 0.f);
        *(float4*)(t1o + (size_t)g * MH + cbase) = v;
    }
}

// ===========================================================================
// k_out2: out = t1o @ Wo2.T + bo2.
// ===========================================================================
__global__ __launch_bounds__(256, 4) void k_out2(
    const float* __restrict__ t1o, const float* __restrict__ Wo2, const float* __restrict__ bo2,
    float* __restrict__ out)
{
    __shared__ float ts[64 * 65];
    const int tid  = threadIdx.x;
    const int lane = tid & 63;
    const int node0 = blockIdx.x * 64;
    const int g = min(node0 + lane, NN - 1);
    const bool valid = (node0 + lane) < NN;

    for (int i = tid; i < 1024; i += 256) {
        int n = i >> 4, k4 = i & 15;
        int gr = min(node0 + n, NN - 1);
        float4 v = ((const float4*)t1o)[(size_t)gr * 16 + k4];
        float* d = &ts[n * 65 + k4 * 4];
        d[0] = v.x; d[1] = v.y; d[2] = v.z; d[3] = v.w;
    }
    __syncthreads();

    float acc[16];
    #pragma unroll
    for (int i = 0; i < 16; ++i) acc[i] = 0.f;
    for (int kt = 0; kt < 8; ++kt) {
        float tv[8];
        #pragma unroll
        for (int i = 0; i < 8; ++i) tv[i] = ts[lane * 65 + kt * 8 + i];
        #pragma unroll
        for (int jj = 0; jj < 16; ++jj) {
            const float* wr = Wo2 + (size_t)jj * MH + kt * 8;
            acc[jj] += tv[0]*wr[0] + tv[1]*wr[1] + tv[2]*wr[2] + tv[3]*wr[3]
                     + tv[4]*wr[4] + tv[5]*wr[5] + tv[6]*wr[6] + tv[7]*wr[7];
        }
    }
    if (valid) {
        float* op = out + (size_t)g * OUT_D;
        #pragma unroll
        for (int c4 = 0; c4 < 4; ++c4) {
            float4 v;
            v.x = acc[c4*4+0] + bo2[c4*4+0];
            v.y = acc[c4*4+1] + bo2[c4*4+1];
            v.z = acc[c4*4+2] + bo2[c4*4+2];
            v.w = acc[c4*4+3] + bo2[c4*4+3];
            *(float4*)(op + c4 * 4) = v;
        }
    }
}

// ---------------------------------------------------------------------------
// Workspace (~89.2 MB). Regions keep f32 sizes; H0/H1 store bf16 in the
// first half of their regions. Aliases: t1=H0, t1o=H1, Qb=H0, Rb=H1.
// Scan block-sums live in H1 (dead during CSR build).
// ---------------------------------------------------------------------------
extern "C" void kernel_launch(void* const* d_in, const int* in_sizes, int n_in,
                              void* d_out, int out_size, void* d_ws, size_t ws_size,
                              hipStream_t stream)
{
    const float* x    = (const float*)d_in[0];
    const int*   ei   = (const int*)d_in[1];
    const float* Win1 = (const float*)d_in[2];
    const float* bin1 = (const float*)d_in[3];
    const float* Win2 = (const float*)d_in[4];
    const float* bin2 = (const float*)d_in[5];
    const float* Wm1  = (const float*)d_in[6];
    const float* bm1  = (const float*)d_in[7];
    const float* Wm2  = (const float*)d_in[8];
    const float* bm2  = (const float*)d_in[9];
    const float* Wd1  = (const float*)d_in[10];
    const float* Wd2  = (const float*)d_in[11];
    const float* Wo1  = (const float*)d_in[12];
    const float* bo1  = (const float*)d_in[13];
    const float* Wo2  = (const float*)d_in[14];
    const float* bo2  = (const float*)d_in[15];
    float* out = (float*)d_out;

    float* ws = (float*)d_ws;
    float* h  = ws;                            // N*256
    float* As = h  + (size_t)NN * HID;         // N*64
    float* Bs = As + (size_t)NN * MH;          // N*64
    float* H0 = Bs + (size_t)NN * MH;          // N*256 region
    float* H1 = H0 + (size_t)NN * HID;         // N*256 region
    float* P  = H1 + (size_t)NN * HID;         // E*16
    float* M  = P  + (size_t)EE * 16;          // N*16
    int* deg    = (int*)(M + (size_t)NN * 16); // N
    int* off    = deg + NN;                    // N+1
    int* cursor = off + NN + 1;                // N
    int* inc    = cursor + NN;                 // 2E
    int* inc2   = inc + 2 * EE;                // 2E
    float* t1  = H0;                           // alias
    float* t1o = H1;                           // alias
    float* Qb  = H0;                           // alias
    float* Rb  = H1;                           // alias
    unsigned short* H0b = (unsigned short*)H0; // bf16 view (first half)
    unsigned short* H1b = (unsigned short*)H1;
    int* bsum = (int*)H1;                      // 250 ints, dead region at scan time

    const int NB = (NN + 63) / 64;             // 313

    // CSR build (parallel scan: 250x80 local -> 1-block top -> add base)
    hipMemsetAsync(deg, 0, NN * sizeof(int), stream);
    k_deg<<<(EE + 255) / 256, 256, 0, stream>>>(ei, deg);
    k_scan_a<<<250, 128, 0, stream>>>(deg, off, bsum);
    k_scan_b<<<1, 256, 0, stream>>>(bsum);
    k_scan_c<<<(NN + 255) / 256, 256, 0, stream>>>(bsum, off, cursor);
    k_scatter<<<(EE + 255) / 256, 256, 0, stream>>>(ei, cursor, inc, inc2);

    // node MLP + per-edge P/Q/R (no atomics) + CSR-gathered M
    k_mlp1<<<dim3(NB, 4), 256, 0, stream>>>(x, Win1, bin1, t1);
    k_mlp2<<<dim3(NB, 4), 256, 0, stream>>>(t1, Win2, bin2, h);
    k_mlp3<<<dim3(NB, 4), 256, 0, stream>>>(h, Wm1, As, Bs);
    k_edge_msg<<<EE / 64, 256, 0, stream>>>(ei, As, Bs, bm1, Wm2, bm2, P, Qb, Rb);
    k_nodeM<<<NN / 16, 256, 0, stream>>>(inc, off, Qb, Rb, M);

    // diffusion (H in bf16, packed per-lane layout)
    k_node_H<<<NN / 16, 256, 0, stream>>>(h, Wd1, Wd2, H0b);
    k_sheaf0<<<NN / 4, 256, 0, stream>>>(inc, inc2, off, P, M, H0b, h, H1b,
                                         Wd1 + 16, Wd2 + 4096);
    k_sheaf1<<<NN / 4, 256, 0, stream>>>(inc, inc2, off, P, M, H1b, h);

    // output MLP
    k_out1<<<dim3(NB, 4), 256, 0, stream>>>(h, Wo1, bo1, t1o);
    k_out2<<<NB, 256, 0, stream>>>(t1o, Wo2, bo2, out);
}

// Round 7
// 484.692 us; speedup vs baseline: 2.3972x; 1.0028x over previous
//
#include <hip/hip_runtime.h>

constexpr int NN   = 20000;
constexpr int EE   = 200000;
constexpr int IN_D = 500;
constexpr int HID  = 256;
constexpr int OUT_D= 16;
constexpr int MH   = 64;

// bf16 helpers (internal H storage only)
__device__ __forceinline__ float bf2f(unsigned short s) {
    return __uint_as_float((unsigned)s << 16);
}
__device__ __forceinline__ unsigned short f2bf(float f) {
    unsigned u = __float_as_uint(f);
    unsigned r = u + 0x7FFF + ((u >> 16) & 1);   // round-to-nearest-even
    return (unsigned short)(r >> 16);
}

// ===========================================================================
// CSR incidence build. inc entry = edge*2 + is_dst; inc2 entry = other node.
// ===========================================================================
__global__ __launch_bounds__(256) void k_deg(const int* __restrict__ ei, int* __restrict__ deg)
{
    int e = blockIdx.x * 256 + threadIdx.x;
    if (e < EE) {
        atomicAdd(deg + ei[e], 1);
        atomicAdd(deg + ei[EE + e], 1);
    }
}

// Parallel scan, 3 kernels. Block sums parked in dead H1 region.
__global__ __launch_bounds__(128) void k_scan_a(const int* __restrict__ deg,
                                                int* __restrict__ off, int* __restrict__ bsum)
{
    __shared__ int s[128];
    const int b = blockIdx.x, tid = threadIdx.x;
    const int n = b * 80 + tid;
    int v = (tid < 80) ? deg[n] : 0;
    s[tid] = v;
    __syncthreads();
    for (int o = 1; o < 128; o <<= 1) {
        int x = 0;
        if (tid >= o) x = s[tid - o];
        __syncthreads();
        if (tid >= o) s[tid] += x;
        __syncthreads();
    }
    if (tid < 80) off[n] = s[tid] - v;     // local exclusive prefix
    if (tid == 127) bsum[b] = s[127];      // block total
}

__global__ __launch_bounds__(256) void k_scan_b(int* __restrict__ bsum)
{
    __shared__ int s[256];
    const int tid = threadIdx.x;
    int v = (tid < 250) ? bsum[tid] : 0;
    s[tid] = v;
    __syncthreads();
    for (int o = 1; o < 256; o <<= 1) {
        int x = 0;
        if (tid >= o) x = s[tid - o];
        __syncthreads();
        if (tid >= o) s[tid] += x;
        __syncthreads();
    }
    if (tid < 250) bsum[tid] = s[tid] - v; // exclusive
}

__global__ __launch_bounds__(256) void k_scan_c(const int* __restrict__ bsum,
                                                int* __restrict__ off, int* __restrict__ cursor)
{
    const int n = blockIdx.x * 256 + threadIdx.x;
    if (n < NN) {
        int o = off[n] + bsum[n / 80];
        off[n] = o;
        cursor[n] = o;
    }
    if (n == 0) off[NN] = 2 * EE;
}

__global__ __launch_bounds__(256) void k_scatter(const int* __restrict__ ei,
                                                 int* __restrict__ cursor,
                                                 int* __restrict__ inc, int* __restrict__ inc2)
{
    int e = blockIdx.x * 256 + threadIdx.x;
    if (e < EE) {
        int s = ei[e], d = ei[EE + e];
        int p = atomicAdd(cursor + s, 1); inc[p] = e * 2;     inc2[p] = d;
        p = atomicAdd(cursor + d, 1);     inc[p] = e * 2 + 1; inc2[p] = s;
    }
}

// ===========================================================================
// k_mlp1: t1 = relu(x @ Win1.T + bin1).  grid (N/64, 4).
// Wave-uniform weight rows -> scalar-pipe weight loads.
// ===========================================================================
__global__ __launch_bounds__(256, 4) void k_mlp1(
    const float* __restrict__ x, const float* __restrict__ Win1, const float* __restrict__ bin1,
    float* __restrict__ t1)
{
    __shared__ float xs[64 * 101];
    const int tid  = threadIdx.x;
    const int w    = __builtin_amdgcn_readfirstlane(tid >> 6);
    const int lane = tid & 63;
    const int node0 = blockIdx.x * 64;
    const int cbase = blockIdx.y * 16 + w * 4;
    const int g = min(node0 + lane, NN - 1);
    const bool valid = (node0 + lane) < NN;

    float acc[4] = {0.f, 0.f, 0.f, 0.f};

    for (int j = 0; j < 5; ++j) {
        __syncthreads();
        for (int i = tid; i < 1600; i += 256) {
            int n = i / 25, k4 = i % 25;
            int gr = min(node0 + n, NN - 1);
            float4 v = ((const float4*)x)[(size_t)gr * 125 + j * 25 + k4];
            float* d = &xs[n * 101 + k4 * 4];
            d[0] = v.x; d[1] = v.y; d[2] = v.z; d[3] = v.w;
        }
        __syncthreads();
        for (int kt = 0; kt < 25; ++kt) {
            float x0 = xs[lane * 101 + kt * 4 + 0];
            float x1 = xs[lane * 101 + kt * 4 + 1];
            float x2 = xs[lane * 101 + kt * 4 + 2];
            float x3 = xs[lane * 101 + kt * 4 + 3];
            #pragma unroll
            for (int cc = 0; cc < 4; ++cc) {
                const float* wr = Win1 + (size_t)(cbase + cc) * IN_D + j * 100 + kt * 4;
                acc[cc] += x0 * wr[0] + x1 * wr[1] + x2 * wr[2] + x3 * wr[3];
            }
        }
    }
    if (valid) {
        float4 v;
        v.x = fmaxf(acc[0] + bin1[cbase + 0], 0.f);
        v.y = fmaxf(acc[1] + bin1[cbase + 1], 0.f);
        v.z = fmaxf(acc[2] + bin1[cbase + 2], 0.f);
        v.w = fmaxf(acc[3] + bin1[cbase + 3], 0.f);
        *(float4*)(t1 + (size_t)g * MH + cbase) = v;
    }
}

// ===========================================================================
// k_mlp2: h = t1 @ Win2.T + bin2.  grid (N/64, 4).
// ===========================================================================
__global__ __launch_bounds__(256, 4) void k_mlp2(
    const float* __restrict__ t1, const float* __restrict__ Win2, const float* __restrict__ bin2,
    float* __restrict__ h)
{
    __shared__ float ts[64 * 65];
    const int tid  = threadIdx.x;
    const int w    = __builtin_amdgcn_readfirstlane(tid >> 6);
    const int lane = tid & 63;
    const int node0 = blockIdx.x * 64;
    const int cbase = blockIdx.y * 64 + w * 16;
    const int g = min(node0 + lane, NN - 1);
    const bool valid = (node0 + lane) < NN;

    for (int i = tid; i < 1024; i += 256) {
        int n = i >> 4, k4 = i & 15;
        int gr = min(node0 + n, NN - 1);
        float4 v = ((const float4*)t1)[(size_t)gr * 16 + k4];
        float* d = &ts[n * 65 + k4 * 4];
        d[0] = v.x; d[1] = v.y; d[2] = v.z; d[3] = v.w;
    }
    __syncthreads();

    float acc[16];
    #pragma unroll
    for (int i = 0; i < 16; ++i) acc[i] = 0.f;
    for (int kt = 0; kt < 8; ++kt) {
        float tv[8];
        #pragma unroll
        for (int i = 0; i < 8; ++i) tv[i] = ts[lane * 65 + kt * 8 + i];
        #pragma unroll
        for (int cc = 0; cc < 16; ++cc) {
            const float* wr = Win2 + (size_t)(cbase + cc) * MH + kt * 8;
            acc[cc] += tv[0]*wr[0] + tv[1]*wr[1] + tv[2]*wr[2] + tv[3]*wr[3]
                     + tv[4]*wr[4] + tv[5]*wr[5] + tv[6]*wr[6] + tv[7]*wr[7];
        }
    }
    if (valid) {
        float* hp = h + (size_t)g * HID + cbase;
        #pragma unroll
        for (int c4 = 0; c4 < 4; ++c4) {
            float4 v;
            v.x = acc[c4*4+0] + bin2[cbase + c4*4+0];
            v.y = acc[c4*4+1] + bin2[cbase + c4*4+1];
            v.z = acc[c4*4+2] + bin2[cbase + c4*4+2];
            v.w = acc[c4*4+3] + bin2[cbase + c4*4+3];
            *(float4*)(hp + c4 * 4) = v;
        }
    }
}

// ===========================================================================
// k_mlp3: AB[n] = [h@Wa.T ; h@Wb.T] interleaved per node (128 floats/node).
// grid (N/64, 4). Row stride 128: A at cols 0-63, B at cols 64-127 -> edge
// gather reads ONE contiguous 512B region per endpoint. Bit-exact layout chg.
// ===========================================================================
__global__ __launch_bounds__(256, 4) void k_mlp3(
    const float* __restrict__ h, const float* __restrict__ Wm1,
    float* __restrict__ AB)
{
    __shared__ float hsm[64 * 65];
    const int tid  = threadIdx.x;
    const int w    = __builtin_amdgcn_readfirstlane(tid >> 6);
    const int lane = tid & 63;
    const int node0 = blockIdx.x * 64;
    const int vcb = blockIdx.y * 32 + w * 8;
    const int which = vcb >> 6;
    const int cb = vcb & 63;
    const int g = min(node0 + lane, NN - 1);
    const bool valid = (node0 + lane) < NN;

    float acc[8];
    #pragma unroll
    for (int i = 0; i < 8; ++i) acc[i] = 0.f;

    for (int ch = 0; ch < 4; ++ch) {
        __syncthreads();
        for (int i = tid; i < 1024; i += 256) {
            int n = i >> 4, k4 = i & 15;
            int gr = min(node0 + n, NN - 1);
            float4 v = ((const float4*)h)[(size_t)gr * 64 + ch * 16 + k4];
            float* d = &hsm[n * 65 + k4 * 4];
            d[0] = v.x; d[1] = v.y; d[2] = v.z; d[3] = v.w;
        }
        __syncthreads();
        for (int kt = 0; kt < 8; ++kt) {
            float tv[8];
            #pragma unroll
            for (int i = 0; i < 8; ++i) tv[i] = hsm[lane * 65 + kt * 8 + i];
            #pragma unroll
            for (int jj = 0; jj < 8; ++jj) {
                const float* wr = Wm1 + (size_t)(cb + jj) * (2 * HID) + which * HID
                                + ch * 64 + kt * 8;
                acc[jj] += tv[0]*wr[0] + tv[1]*wr[1] + tv[2]*wr[2] + tv[3]*wr[3]
                         + tv[4]*wr[4] + tv[5]*wr[5] + tv[6]*wr[6] + tv[7]*wr[7];
            }
        }
    }
    if (valid) {
        float* dst = AB + (size_t)g * 128 + which * 64 + cb;
        float4 v0, v1;
        v0.x = acc[0]; v0.y = acc[1]; v0.z = acc[2]; v0.w = acc[3];
        v1.x = acc[4]; v1.y = acc[5]; v1.z = acc[6]; v1.w = acc[7];
        *(float4*)(dst + 0) = v0;
        *(float4*)(dst + 4) = v1;
    }
}

// ===========================================================================
// k_edge_msg — 64 edges/block; AB interleaved gather (one 512B region per
// endpoint instead of two 256B regions 5MB apart).
// ===========================================================================
__global__ __launch_bounds__(256, 4) void k_edge_msg(
    const int* __restrict__ ei, const float* __restrict__ AB,
    const float* __restrict__ bm1, const float* __restrict__ Wm2, const float* __restrict__ bm2,
    float* __restrict__ P, float* __restrict__ Qb, float* __restrict__ Rb)
{
    __shared__ float smem[128 * 64];
    __shared__ float wm2s[16 * 68];
    const int tid = threadIdx.x;
    const int w = tid >> 6, t = tid & 63;
    const int e0 = blockIdx.x * 64;

    for (int i = tid; i < 1024; i += 256)
        wm2s[(i >> 6) * 68 + (i & 63)] = Wm2[i];

    const float bm = bm1[t];
    const int tc = t >> 2, tr = t & 3;

    for (int r = 0; r < 16; ++r) {
        const int el = w * 16 + r;
        const int e = e0 + el;
        const int src = ei[e], dst = ei[EE + e];
        const float* su = AB + (size_t)src * 128;
        const float* du = AB + (size_t)dst * 128;
        float a_s = su[t];
        float b_s = su[64 + t];
        float a_d = du[t];
        float b_d = du[64 + t];
        const int row0 = el * 2, row1 = el * 2 + 1;
        smem[row0 * 64 + (((tc) + (row0 >> 2)) & 15) * 4 + tr] = fmaxf(a_s + b_d + bm, 0.f);
        smem[row1 * 64 + (((tc) + (row1 >> 2)) & 15) * 4 + tr] = fmaxf(a_d + b_s + bm, 0.f);
    }
    __syncthreads();

    float acc[4][2];
    {
        const int pg = tid & 31;
        const int jg = tid >> 5;
        const int j0 = jg * 2;
        #pragma unroll
        for (int i = 0; i < 4; ++i) { acc[i][0] = 0.f; acc[i][1] = 0.f; }

        const float4* w0 = (const float4*)&wm2s[(j0 + 0) * 68];
        const float4* w1 = (const float4*)&wm2s[(j0 + 1) * 68];
        const float4* p0 = (const float4*)&smem[(4 * pg + 0) * 64];
        const float4* p1 = (const float4*)&smem[(4 * pg + 1) * 64];
        const float4* p2 = (const float4*)&smem[(4 * pg + 2) * 64];
        const float4* p3 = (const float4*)&smem[(4 * pg + 3) * 64];

        #pragma unroll
        for (int k4 = 0; k4 < 16; ++k4) {
            const int ch = (k4 + pg) & 15;
            float4 wv0 = w0[k4], wv1 = w1[k4];
            float4 a = p0[ch], b = p1[ch], c = p2[ch], d = p3[ch];
            acc[0][0] += a.x*wv0.x + a.y*wv0.y + a.z*wv0.z + a.w*wv0.w;
            acc[0][1] += a.x*wv1.x + a.y*wv1.y + a.z*wv1.z + a.w*wv1.w;
            acc[1][0] += b.x*wv0.x + b.y*wv0.y + b.z*wv0.z + b.w*wv0.w;
            acc[1][1] += b.x*wv1.x + b.y*wv1.y + b.z*wv1.z + b.w*wv1.w;
            acc[2][0] += c.x*wv0.x + c.y*wv0.y + c.z*wv0.z + c.w*wv0.w;
            acc[2][1] += c.x*wv1.x + c.y*wv1.y + c.z*wv1.z + c.w*wv1.w;
            acc[3][0] += d.x*wv0.x + d.y*wv0.y + d.z*wv0.z + d.w*wv0.w;
            acc[3][1] += d.x*wv1.x + d.y*wv1.y + d.z*wv1.z + d.w*wv1.w;
        }
    }
    __syncthreads();

    float* fls = smem;
    {
        const int pg = tid & 31;
        const int jg = tid >> 5;
        const int j0 = jg * 2;
        float bm2a = bm2[j0], bm2b = bm2[j0 + 1];
        #pragma unroll
        for (int i = 0; i < 4; ++i) {
            fls[(4 * pg + i) * 17 + j0]     = acc[i][0] + bm2a;
            fls[(4 * pg + i) * 17 + j0 + 1] = acc[i][1] + bm2b;
        }
    }
    __syncthreads();

    {
        const int el = tid >> 2, cg = tid & 3;
        const float* f0 = &fls[(el * 2 + 0) * 17];
        const float* f1 = &fls[(el * 2 + 1) * 17];
        float a0 = f0[0*4+cg], a1 = f0[1*4+cg], a2 = f0[2*4+cg], a3 = f0[3*4+cg];
        float b0 = f1[0*4+cg], b1 = f1[1*4+cg], b2 = f1[2*4+cg], b3 = f1[3*4+cg];
        float4 pp, qq, rr;
        {
            float c0, c1, c2, c3;
            c0 = f1[0]; c1 = f1[4]; c2 = f1[8]; c3 = f1[12];
            pp.x = a0*c0 + a1*c1 + a2*c2 + a3*c3;
            rr.x = b0*c0 + b1*c1 + b2*c2 + b3*c3;
            c0 = f1[1]; c1 = f1[5]; c2 = f1[9]; c3 = f1[13];
            pp.y = a0*c0 + a1*c1 + a2*c2 + a3*c3;
            rr.y = b0*c0 + b1*c1 + b2*c2 + b3*c3;
            c0 = f1[2]; c1 = f1[6]; c2 = f1[10]; c3 = f1[14];
            pp.z = a0*c0 + a1*c1 + a2*c2 + a3*c3;
            rr.z = b0*c0 + b1*c1 + b2*c2 + b3*c3;
            c0 = f1[3]; c1 = f1[7]; c2 = f1[11]; c3 = f1[15];
            pp.w = a0*c0 + a1*c1 + a2*c2 + a3*c3;
            rr.w = b0*c0 + b1*c1 + b2*c2 + b3*c3;
            c0 = f0[0]; c1 = f0[4]; c2 = f0[8]; c3 = f0[12];
            qq.x = a0*c0 + a1*c1 + a2*c2 + a3*c3;
            c0 = f0[1]; c1 = f0[5]; c2 = f0[9]; c3 = f0[13];
            qq.y = a0*c0 + a1*c1 + a2*c2 + a3*c3;
            c0 = f0[2]; c1 = f0[6]; c2 = f0[10]; c3 = f0[14];
            qq.z = a0*c0 + a1*c1 + a2*c2 + a3*c3;
            c0 = f0[3]; c1 = f0[7]; c2 = f0[11]; c3 = f0[15];
            qq.w = a0*c0 + a1*c1 + a2*c2 + a3*c3;
        }
        const int eg = e0 + el;
        *(float4*)(P  + (size_t)eg * 16 + cg * 4) = pp;
        *(float4*)(Qb + (size_t)eg * 16 + cg * 4) = qq;
        *(float4*)(Rb + (size_t)eg * 16 + cg * 4) = rr;
    }
}

// ===========================================================================
// k_nodeM — M[n] = Σ Qb (src-inc) + Σ Rb (dst-inc) via CSR, no atomics.
// ===========================================================================
__global__ __launch_bounds__(256) void k_nodeM(
    const int* __restrict__ inc, const int* __restrict__ off,
    const float* __restrict__ Qb, const float* __restrict__ Rb,
    float* __restrict__ M)
{
    const int tid = threadIdx.x;
    const int ni = tid >> 4, comp = tid & 15;
    const int n = blockIdx.x * 16 + ni;
    const int p0 = off[n], p1 = off[n + 1];
    float s = 0.f;
    for (int p = p0; p < p1; ++p) {
        int v = inc[p];
        const float* src = (v & 1) ? Rb : Qb;
        s += src[(size_t)(v >> 1) * 16 + comp];
    }
    M[(size_t)n * 16 + comp] = s;
}

// ===========================================================================
// k_node_H — H0 = (Wd1.T @ xb) @ Wd2.T per node, stored as BF16 (packed
// per-lane layout H[n][t*4+k]). Wd2 read directly from global (L2-resident
// broadcast); no wt LDS, no barriers (tl[w] is wave-private).
// ===========================================================================
__global__ __launch_bounds__(256) void k_node_H(
    const float* __restrict__ xb,
    const float* __restrict__ Wd1l, const float* __restrict__ Wd2l,
    unsigned short* __restrict__ H)
{
    __shared__ float tl[4][4][64];
    const int tid = threadIdx.x;
    const int w = __builtin_amdgcn_readfirstlane(tid >> 6);
    const int t = tid & 63;

    float wd1[16];
    #pragma unroll
    for (int i = 0; i < 16; ++i) wd1[i] = Wd1l[i];
    const float* wrow = Wd2l + t * 64;

    for (int rep = 0; rep < 4; ++rep) {
        const int n = blockIdx.x * 16 + w * 4 + rep;
        float xv[4];
        #pragma unroll
        for (int j = 0; j < 4; ++j) xv[j] = xb[(size_t)n * HID + j * 64 + t];
        #pragma unroll
        for (int i = 0; i < 4; ++i)
            tl[w][i][t] = wd1[0 + i] * xv[0] + wd1[4 + i] * xv[1] +
                          wd1[8 + i] * xv[2] + wd1[12 + i] * xv[3];
        float a0 = 0, a1 = 0, a2 = 0, a3 = 0;
        #pragma unroll
        for (int f = 0; f < 64; f += 4) {
            float4 wv = *(const float4*)(wrow + f);
            float4 t0 = *(const float4*)&tl[w][0][f];
            float4 t1 = *(const float4*)&tl[w][1][f];
            float4 t2 = *(const float4*)&tl[w][2][f];
            float4 t3 = *(const float4*)&tl[w][3][f];
            a0 += t0.x * wv.x + t0.y * wv.y + t0.z * wv.z + t0.w * wv.w;
            a1 += t1.x * wv.x + t1.y * wv.y + t1.z * wv.z + t1.w * wv.w;
            a2 += t2.x * wv.x + t2.y * wv.y + t2.z * wv.z + t2.w * wv.w;
            a3 += t3.x * wv.x + t3.y * wv.y + t3.z * wv.z + t3.w * wv.w;
        }
        unsigned lo = (unsigned)f2bf(a0) | ((unsigned)f2bf(a1) << 16);
        unsigned hi = (unsigned)f2bf(a2) | ((unsigned)f2bf(a3) << 16);
        *(uint2*)(H + (size_t)n * HID + (t << 2)) = make_uint2(lo, hi);
    }
}

// ===========================================================================
// sheaf gather — pair unroll, wave-uniform scalar index/P loads, packed-bf16
// H. Measured best (rounds 0-6): quad unroll regressed via SGPR->occupancy;
// LDS staging and readlane batching regressed via VALU/latency. DO NOT
// restructure; the kernel runs at the random-granule fabric-BW ceiling.
// ===========================================================================
__device__ __forceinline__ void sheaf_apply(int v, uint2 u, const float pe[16], float acc[4])
{
    const float h0 = __uint_as_float(u.x << 16);
    const float h1 = __uint_as_float(u.x & 0xFFFF0000u);
    const float h2 = __uint_as_float(u.y << 16);
    const float h3 = __uint_as_float(u.y & 0xFFFF0000u);
    if (!(v & 1)) {
        #pragma unroll
        for (int j = 0; j < 4; ++j)
            acc[j] -= pe[j*4+0]*h0 + pe[j*4+1]*h1 + pe[j*4+2]*h2 + pe[j*4+3]*h3;
    } else {
        #pragma unroll
        for (int j = 0; j < 4; ++j)
            acc[j] -= pe[0*4+j]*h0 + pe[1*4+j]*h1 + pe[2*4+j]*h2 + pe[3*4+j]*h3;
    }
}

__device__ __forceinline__ void sheaf_gather(
    const int* __restrict__ inc, const int* __restrict__ inc2,
    const float* __restrict__ P, const unsigned short* __restrict__ Hin,
    int p0, int p1, int t, float acc[4])
{
    int p = p0;
    for (; p + 2 <= p1; p += 2) {
        const int vA = __builtin_amdgcn_readfirstlane(inc[p]);
        const int oA = __builtin_amdgcn_readfirstlane(inc2[p]);
        const int vB = __builtin_amdgcn_readfirstlane(inc[p + 1]);
        const int oB = __builtin_amdgcn_readfirstlane(inc2[p + 1]);
        const uint2 uA = *(const uint2*)(Hin + (size_t)oA * HID + (t << 2));
        const uint2 uB = *(const uint2*)(Hin + (size_t)oB * HID + (t << 2));
        const float* PA = P + (size_t)(vA >> 1) * 16;
        const float* PB = P + (size_t)(vB >> 1) * 16;
        float pa[16], pb[16];
        #pragma unroll
        for (int i = 0; i < 16; ++i) pa[i] = PA[i];
        #pragma unroll
        for (int i = 0; i < 16; ++i) pb[i] = PB[i];
        sheaf_apply(vA, uA, pa, acc);
        sheaf_apply(vB, uB, pb, acc);
    }
    if (p < p1) {
        const int v = __builtin_amdgcn_readfirstlane(inc[p]);
        const int o = __builtin_amdgcn_readfirstlane(inc2[p]);
        const uint2 u = *(const uint2*)(Hin + (size_t)o * HID + (t << 2));
        const float* Pe = P + (size_t)(v >> 1) * 16;
        float pe[16];
        #pragma unroll
        for (int i = 0; i < 16; ++i) pe[i] = Pe[i];
        sheaf_apply(v, u, pe, acc);
    }
}

// ===========================================================================
// k_sheaf0 — layer 0: LH gather + xb update + fused next-layer H (bf16 out).
// Wd2 from global (L2-resident); LDS = tl only (4 KB); barrier-free.
// ===========================================================================
__global__ __launch_bounds__(256) void k_sheaf0(
    const int* __restrict__ inc, const int* __restrict__ inc2, const int* __restrict__ off,
    const float* __restrict__ P, const float* __restrict__ M,
    const unsigned short* __restrict__ Hin, float* __restrict__ h,
    unsigned short* __restrict__ Hout,
    const float* __restrict__ Wd1l, const float* __restrict__ Wd2l)
{
    __shared__ float tl[4][4][64];
    const int tid = threadIdx.x;
    const int w = __builtin_amdgcn_readfirstlane(tid >> 6);
    const int t = tid & 63;

    float wd1[16];
    #pragma unroll
    for (int i = 0; i < 16; ++i) wd1[i] = Wd1l[i];

    const int n = blockIdx.x * 4 + w;
    const uint2 un = *(const uint2*)(Hin + (size_t)n * HID + (t << 2));
    float Hn[4];
    Hn[0] = __uint_as_float(un.x << 16);
    Hn[1] = __uint_as_float(un.x & 0xFFFF0000u);
    Hn[2] = __uint_as_float(un.y << 16);
    Hn[3] = __uint_as_float(un.y & 0xFFFF0000u);
    float Mn[16];
    #pragma unroll
    for (int c = 0; c < 16; ++c) Mn[c] = M[(size_t)n * 16 + c];

    float acc[4];
    #pragma unroll
    for (int j = 0; j < 4; ++j)
        acc[j] = Mn[j*4+0]*Hn[0] + Mn[j*4+1]*Hn[1] + Mn[j*4+2]*Hn[2] + Mn[j*4+3]*Hn[3];

    const int p0 = __builtin_amdgcn_readfirstlane(off[n]);
    const int p1 = __builtin_amdgcn_readfirstlane(off[n + 1]);
    sheaf_gather(inc, inc2, P, Hin, p0, p1, t, acc);

    float xv[4];
    #pragma unroll
    for (int j = 0; j < 4; ++j) {
        size_t idx = (size_t)n * HID + j * 64 + t;
        float vv = h[idx] - fmaxf(acc[j], 0.f);
        h[idx] = vv;
        xv[j] = vv;
    }

    #pragma unroll
    for (int i = 0; i < 4; ++i)
        tl[w][i][t] = wd1[0 + i] * xv[0] + wd1[4 + i] * xv[1] +
                      wd1[8 + i] * xv[2] + wd1[12 + i] * xv[3];
    // no __syncthreads(): tl[w] is wave-private; DS ops complete in order.
    const float* wrow = Wd2l + t * 64;
    float a0 = 0, a1 = 0, a2 = 0, a3 = 0;
    #pragma unroll
    for (int f = 0; f < 64; f += 4) {
        float4 wv = *(const float4*)(wrow + f);
        float4 t0 = *(const float4*)&tl[w][0][f];
        float4 t1 = *(const float4*)&tl[w][1][f];
        float4 t2 = *(const float4*)&tl[w][2][f];
        float4 t3 = *(const float4*)&tl[w][3][f];
        a0 += t0.x * wv.x + t0.y * wv.y + t0.z * wv.z + t0.w * wv.w;
        a1 += t1.x * wv.x + t1.y * wv.y + t1.z * wv.z + t1.w * wv.w;
        a2 += t2.x * wv.x + t2.y * wv.y + t2.z * wv.z + t2.w * wv.w;
        a3 += t3.x * wv.x + t3.y * wv.y + t3.z * wv.z + t3.w * wv.w;
    }
    unsigned lo = (unsigned)f2bf(a0) | ((unsigned)f2bf(a1) << 16);
    unsigned hi = (unsigned)f2bf(a2) | ((unsigned)f2bf(a3) << 16);
    *(uint2*)(Hout + (size_t)n * HID + (t << 2)) = make_uint2(lo, hi);
}

// ===========================================================================
// k_sheaf1 — layer 1: LH gather + xb update only. ZERO LDS.
// ===========================================================================
__global__ __launch_bounds__(256) void k_sheaf1(
    const int* __restrict__ inc, const int* __restrict__ inc2, const int* __restrict__ off,
    const float* __restrict__ P, const float* __restrict__ M,
    const unsigned short* __restrict__ Hin, float* __restrict__ h)
{
    const int tid = threadIdx.x;
    const int w = __builtin_amdgcn_readfirstlane(tid >> 6);
    const int t = tid & 63;
    const int n = blockIdx.x * 4 + w;

    const uint2 un = *(const uint2*)(Hin + (size_t)n * HID + (t << 2));
    float Hn[4];
    Hn[0] = __uint_as_float(un.x << 16);
    Hn[1] = __uint_as_float(un.x & 0xFFFF0000u);
    Hn[2] = __uint_as_float(un.y << 16);
    Hn[3] = __uint_as_float(un.y & 0xFFFF0000u);
    float Mn[16];
    #pragma unroll
    for (int c = 0; c < 16; ++c) Mn[c] = M[(size_t)n * 16 + c];

    float acc[4];
    #pragma unroll
    for (int j = 0; j < 4; ++j)
        acc[j] = Mn[j*4+0]*Hn[0] + Mn[j*4+1]*Hn[1] + Mn[j*4+2]*Hn[2] + Mn[j*4+3]*Hn[3];

    const int p0 = __builtin_amdgcn_readfirstlane(off[n]);
    const int p1 = __builtin_amdgcn_readfirstlane(off[n + 1]);
    sheaf_gather(inc, inc2, P, Hin, p0, p1, t, acc);

    #pragma unroll
    for (int j = 0; j < 4; ++j) {
        size_t idx = (size_t)n * HID + j * 64 + t;
        h[idx] = h[idx] - fmaxf(acc[j], 0.f);
    }
}

// ===========================================================================
// k_out1: t1o = relu(xb @ Wo1.T + bo1).  grid (N/64, 4).
// ===========================================================================
__global__ __launch_bounds__(256, 4) void k_out1(
    const float* __restrict__ xb, const float* __restrict__ Wo1, const float* __restrict__ bo1,
    float* __restrict__ t1o)
{
    __shared__ float xr[64 * 129];
    const int tid  = threadIdx.x;
    const int w    = __builtin_amdgcn_readfirstlane(tid >> 6);
    const int lane = tid & 63;
    const int node0 = blockIdx.x * 64;
    const int cbase = blockIdx.y * 16 + w * 4;
    const int g = min(node0 + lane, NN - 1);
    const bool valid = (node0 + lane) < NN;

    float acc[4] = {0.f, 0.f, 0.f, 0.f};

    for (int j = 0; j < 2; ++j) {
        __syncthreads();
        for (int i = tid; i < 2048; i += 256) {
            int n = i >> 5, k4 = i & 31;
            int gr = min(node0 + n, NN - 1);
            float4 v = ((const float4*)xb)[(size_t)gr * 64 + j * 32 + k4];
            float* d = &xr[n * 129 + k4 * 4];
            d[0] = v.x; d[1] = v.y; d[2] = v.z; d[3] = v.w;
        }
        __syncthreads();
        for (int kt = 0; kt < 32; ++kt) {
            float x0 = xr[lane * 129 + kt * 4 + 0];
            float x1 = xr[lane * 129 + kt * 4 + 1];
            float x2 = xr[lane * 129 + kt * 4 + 2];
            float x3 = xr[lane * 129 + kt * 4 + 3];
            #pragma unroll
            for (int cc = 0; cc < 4; ++cc) {
                const float* wr = Wo1 + (size_t)(cbase + cc) * HID + j * 128 + kt * 4;
                acc[cc] += x0 * wr[0] + x1 * wr[1] + x2 * wr[2] + x3 * wr[3];
            }
        }
    }
    if (valid) {
        float4 v;
        v.x = fmaxf(acc[0] + bo1[cbase + 0], 0.f);
        v.y = fmaxf(acc[1] + bo1[cbase + 1], 0.f);
        v.z = fmaxf(acc[2] + bo1[cbase + 2], 0.f);
        v.w = fmaxf(acc[3] + bo1[cbase + 3], 0.f);
        *(float4*)(t1o + (size_t)g * MH + cbase) = v;
    }
}

// ===========================================================================
// k_out2: out = t1o @ Wo2.T + bo2.
// ===========================================================================
__global__ __launch_bounds__(256, 4) void k_out2(
    const float* __restrict__ t1o, const float* __restrict__ Wo2, const float* __restrict__ bo2,
    float* __restrict__ out)
{
    __shared__ float ts[64 * 65];
    const int tid  = threadIdx.x;
    const int lane = tid & 63;
    const int node0 = blockIdx.x * 64;
    const int g = min(node0 + lane, NN - 1);
    const bool valid = (node0 + lane) < NN;

    for (int i = tid; i < 1024; i += 256) {
        int n = i >> 4, k4 = i & 15;
        int gr = min(node0 + n, NN - 1);
        float4 v = ((const float4*)t1o)[(size_t)gr * 16 + k4];
        float* d = &ts[n * 65 + k4 * 4];
        d[0] = v.x; d[1] = v.y; d[2] = v.z; d[3] = v.w;
    }
    __syncthreads();

    float acc[16];
    #pragma unroll
    for (int i = 0; i < 16; ++i) acc[i] = 0.f;
    for (int kt = 0; kt < 8; ++kt) {
        float tv[8];
        #pragma unroll
        for (int i = 0; i < 8; ++i) tv[i] = ts[lane * 65 + kt * 8 + i];
        #pragma unroll
        for (int jj = 0; jj < 16; ++jj) {
            const float* wr = Wo2 + (size_t)jj * MH + kt * 8;
            acc[jj] += tv[0]*wr[0] + tv[1]*wr[1] + tv[2]*wr[2] + tv[3]*wr[3]
                     + tv[4]*wr[4] + tv[5]*wr[5] + tv[6]*wr[6] + tv[7]*wr[7];
        }
    }
    if (valid) {
        float* op = out + (size_t)g * OUT_D;
        #pragma unroll
        for (int c4 = 0; c4 < 4; ++c4) {
            float4 v;
            v.x = acc[c4*4+0] + bo2[c4*4+0];
            v.y = acc[c4*4+1] + bo2[c4*4+1];
            v.z = acc[c4*4+2] + bo2[c4*4+2];
            v.w = acc[c4*4+3] + bo2[c4*4+3];
            *(float4*)(op + c4 * 4) = v;
        }
    }
}

// ---------------------------------------------------------------------------
// Workspace (~89.2 MB). AB occupies the old As+Bs footprint (N*128 floats,
// interleaved per node). H0/H1 store bf16 in the first half of their regions.
// Aliases: t1=H0, t1o=H1, Qb=H0, Rb=H1. Scan bsum lives in H1.
// ---------------------------------------------------------------------------
extern "C" void kernel_launch(void* const* d_in, const int* in_sizes, int n_in,
                              void* d_out, int out_size, void* d_ws, size_t ws_size,
                              hipStream_t stream)
{
    const float* x    = (const float*)d_in[0];
    const int*   ei   = (const int*)d_in[1];
    const float* Win1 = (const float*)d_in[2];
    const float* bin1 = (const float*)d_in[3];
    const float* Win2 = (const float*)d_in[4];
    const float* bin2 = (const float*)d_in[5];
    const float* Wm1  = (const float*)d_in[6];
    const float* bm1  = (const float*)d_in[7];
    const float* Wm2  = (const float*)d_in[8];
    const float* bm2  = (const float*)d_in[9];
    const float* Wd1  = (const float*)d_in[10];
    const float* Wd2  = (const float*)d_in[11];
    const float* Wo1  = (const float*)d_in[12];
    const float* bo1  = (const float*)d_in[13];
    const float* Wo2  = (const float*)d_in[14];
    const float* bo2  = (const float*)d_in[15];
    float* out = (float*)d_out;

    float* ws = (float*)d_ws;
    float* h  = ws;                            // N*256
    float* AB = h  + (size_t)NN * HID;         // N*128 (interleaved A|B)
    float* H0 = AB + (size_t)NN * 128;         // N*256 region
    float* H1 = H0 + (size_t)NN * HID;         // N*256 region
    float* P  = H1 + (size_t)NN * HID;         // E*16
    float* M  = P  + (size_t)EE * 16;          // N*16
    int* deg    = (int*)(M + (size_t)NN * 16); // N
    int* off    = deg + NN;                    // N+1
    int* cursor = off + NN + 1;                // N
    int* inc    = cursor + NN;                 // 2E
    int* inc2   = inc + 2 * EE;                // 2E
    float* t1  = H0;                           // alias
    float* t1o = H1;                           // alias
    float* Qb  = H0;                           // alias
    float* Rb  = H1;                           // alias
    unsigned short* H0b = (unsigned short*)H0; // bf16 view (first half)
    unsigned short* H1b = (unsigned short*)H1;
    int* bsum = (int*)H1;                      // 250 ints, dead region at scan time

    const int NB = (NN + 63) / 64;             // 313

    // CSR build (parallel scan: 250x80 local -> 1-block top -> add base)
    hipMemsetAsync(deg, 0, NN * sizeof(int), stream);
    k_deg<<<(EE + 255) / 256, 256, 0, stream>>>(ei, deg);
    k_scan_a<<<250, 128, 0, stream>>>(deg, off, bsum);
    k_scan_b<<<1, 256, 0, stream>>>(bsum);
    k_scan_c<<<(NN + 255) / 256, 256, 0, stream>>>(bsum, off, cursor);
    k_scatter<<<(EE + 255) / 256, 256, 0, stream>>>(ei, cursor, inc, inc2);

    // node MLP + per-edge P/Q/R (no atomics) + CSR-gathered M
    k_mlp1<<<dim3(NB, 4), 256, 0, stream>>>(x, Win1, bin1, t1);
    k_mlp2<<<dim3(NB, 4), 256, 0, stream>>>(t1, Win2, bin2, h);
    k_mlp3<<<dim3(NB, 4), 256, 0, stream>>>(h, Wm1, AB);
    k_edge_msg<<<EE / 64, 256, 0, stream>>>(ei, AB, bm1, Wm2, bm2, P, Qb, Rb);
    k_nodeM<<<NN / 16, 256, 0, stream>>>(inc, off, Qb, Rb, M);

    // diffusion (H in bf16, packed per-lane layout)
    k_node_H<<<NN / 16, 256, 0, stream>>>(h, Wd1, Wd2, H0b);
    k_sheaf0<<<NN / 4, 256, 0, stream>>>(inc, inc2, off, P, M, H0b, h, H1b,
                                         Wd1 + 16, Wd2 + 4096);
    k_sheaf1<<<NN / 4, 256, 0, stream>>>(inc, inc2, off, P, M, H1b, h);

    // output MLP
    k_out1<<<dim3(NB, 4), 256, 0, stream>>>(h, Wo1, bo1, t1o);
    k_out2<<<NB, 256, 0, stream>>>(t1o, Wo2, bo2, out);
}

// Round 8
// 472.191 us; speedup vs baseline: 2.4607x; 1.0265x over previous
//
#include <hip/hip_runtime.h>

constexpr int NN   = 20000;
constexpr int EE   = 200000;
constexpr int IN_D = 500;
constexpr int HID  = 256;
constexpr int OUT_D= 16;
constexpr int MH   = 64;

// bf16 helpers (internal H/P storage only)
__device__ __forceinline__ float bf2f(unsigned short s) {
    return __uint_as_float((unsigned)s << 16);
}
__device__ __forceinline__ unsigned short f2bf(float f) {
    unsigned u = __float_as_uint(f);
    unsigned r = u + 0x7FFF + ((u >> 16) & 1);   // round-to-nearest-even
    return (unsigned short)(r >> 16);
}

// ===========================================================================
// CSR incidence build. inc entry = edge*2 + is_dst; inc2 entry = other node.
// posS/posD record each edge's two CSR slots (for CSR-ordered P2).
// ===========================================================================
__global__ __launch_bounds__(256) void k_deg(const int* __restrict__ ei, int* __restrict__ deg)
{
    int e = blockIdx.x * 256 + threadIdx.x;
    if (e < EE) {
        atomicAdd(deg + ei[e], 1);
        atomicAdd(deg + ei[EE + e], 1);
    }
}

// Parallel scan, 3 kernels. Block sums parked in dead H1 region.
__global__ __launch_bounds__(128) void k_scan_a(const int* __restrict__ deg,
                                                int* __restrict__ off, int* __restrict__ bsum)
{
    __shared__ int s[128];
    const int b = blockIdx.x, tid = threadIdx.x;
    const int n = b * 80 + tid;
    int v = (tid < 80) ? deg[n] : 0;
    s[tid] = v;
    __syncthreads();
    for (int o = 1; o < 128; o <<= 1) {
        int x = 0;
        if (tid >= o) x = s[tid - o];
        __syncthreads();
        if (tid >= o) s[tid] += x;
        __syncthreads();
    }
    if (tid < 80) off[n] = s[tid] - v;     // local exclusive prefix
    if (tid == 127) bsum[b] = s[127];      // block total
}

__global__ __launch_bounds__(256) void k_scan_b(int* __restrict__ bsum)
{
    __shared__ int s[256];
    const int tid = threadIdx.x;
    int v = (tid < 250) ? bsum[tid] : 0;
    s[tid] = v;
    __syncthreads();
    for (int o = 1; o < 256; o <<= 1) {
        int x = 0;
        if (tid >= o) x = s[tid - o];
        __syncthreads();
        if (tid >= o) s[tid] += x;
        __syncthreads();
    }
    if (tid < 250) bsum[tid] = s[tid] - v; // exclusive
}

__global__ __launch_bounds__(256) void k_scan_c(const int* __restrict__ bsum,
                                                int* __restrict__ off, int* __restrict__ cursor)
{
    const int n = blockIdx.x * 256 + threadIdx.x;
    if (n < NN) {
        int o = off[n] + bsum[n / 80];
        off[n] = o;
        cursor[n] = o;
    }
    if (n == 0) off[NN] = 2 * EE;
}

__global__ __launch_bounds__(256) void k_scatter(const int* __restrict__ ei,
                                                 int* __restrict__ cursor,
                                                 int* __restrict__ inc, int* __restrict__ inc2,
                                                 int* __restrict__ posS, int* __restrict__ posD)
{
    int e = blockIdx.x * 256 + threadIdx.x;
    if (e < EE) {
        int s = ei[e], d = ei[EE + e];
        int p = atomicAdd(cursor + s, 1); inc[p] = e * 2;     inc2[p] = d; posS[e] = p;
        p = atomicAdd(cursor + d, 1);     inc[p] = e * 2 + 1; inc2[p] = s; posD[e] = p;
    }
}

// ===========================================================================
// k_mlp1: t1 = relu(x @ Win1.T + bin1).  grid (N/64, 4).
// Wave-uniform weight rows -> scalar-pipe weight loads.
// ===========================================================================
__global__ __launch_bounds__(256, 4) void k_mlp1(
    const float* __restrict__ x, const float* __restrict__ Win1, const float* __restrict__ bin1,
    float* __restrict__ t1)
{
    __shared__ float xs[64 * 101];
    const int tid  = threadIdx.x;
    const int w    = __builtin_amdgcn_readfirstlane(tid >> 6);
    const int lane = tid & 63;
    const int node0 = blockIdx.x * 64;
    const int cbase = blockIdx.y * 16 + w * 4;
    const int g = min(node0 + lane, NN - 1);
    const bool valid = (node0 + lane) < NN;

    float acc[4] = {0.f, 0.f, 0.f, 0.f};

    for (int j = 0; j < 5; ++j) {
        __syncthreads();
        for (int i = tid; i < 1600; i += 256) {
            int n = i / 25, k4 = i % 25;
            int gr = min(node0 + n, NN - 1);
            float4 v = ((const float4*)x)[(size_t)gr * 125 + j * 25 + k4];
            float* d = &xs[n * 101 + k4 * 4];
            d[0] = v.x; d[1] = v.y; d[2] = v.z; d[3] = v.w;
        }
        __syncthreads();
        for (int kt = 0; kt < 25; ++kt) {
            float x0 = xs[lane * 101 + kt * 4 + 0];
            float x1 = xs[lane * 101 + kt * 4 + 1];
            float x2 = xs[lane * 101 + kt * 4 + 2];
            float x3 = xs[lane * 101 + kt * 4 + 3];
            #pragma unroll
            for (int cc = 0; cc < 4; ++cc) {
                const float* wr = Win1 + (size_t)(cbase + cc) * IN_D + j * 100 + kt * 4;
                acc[cc] += x0 * wr[0] + x1 * wr[1] + x2 * wr[2] + x3 * wr[3];
            }
        }
    }
    if (valid) {
        float4 v;
        v.x = fmaxf(acc[0] + bin1[cbase + 0], 0.f);
        v.y = fmaxf(acc[1] + bin1[cbase + 1], 0.f);
        v.z = fmaxf(acc[2] + bin1[cbase + 2], 0.f);
        v.w = fmaxf(acc[3] + bin1[cbase + 3], 0.f);
        *(float4*)(t1 + (size_t)g * MH + cbase) = v;
    }
}

// ===========================================================================
// k_mlp2: h = t1 @ Win2.T + bin2.  grid (N/64, 4).
// ===========================================================================
__global__ __launch_bounds__(256, 4) void k_mlp2(
    const float* __restrict__ t1, const float* __restrict__ Win2, const float* __restrict__ bin2,
    float* __restrict__ h)
{
    __shared__ float ts[64 * 65];
    const int tid  = threadIdx.x;
    const int w    = __builtin_amdgcn_readfirstlane(tid >> 6);
    const int lane = tid & 63;
    const int node0 = blockIdx.x * 64;
    const int cbase = blockIdx.y * 64 + w * 16;
    const int g = min(node0 + lane, NN - 1);
    const bool valid = (node0 + lane) < NN;

    for (int i = tid; i < 1024; i += 256) {
        int n = i >> 4, k4 = i & 15;
        int gr = min(node0 + n, NN - 1);
        float4 v = ((const float4*)t1)[(size_t)gr * 16 + k4];
        float* d = &ts[n * 65 + k4 * 4];
        d[0] = v.x; d[1] = v.y; d[2] = v.z; d[3] = v.w;
    }
    __syncthreads();

    float acc[16];
    #pragma unroll
    for (int i = 0; i < 16; ++i) acc[i] = 0.f;
    for (int kt = 0; kt < 8; ++kt) {
        float tv[8];
        #pragma unroll
        for (int i = 0; i < 8; ++i) tv[i] = ts[lane * 65 + kt * 8 + i];
        #pragma unroll
        for (int cc = 0; cc < 16; ++cc) {
            const float* wr = Win2 + (size_t)(cbase + cc) * MH + kt * 8;
            acc[cc] += tv[0]*wr[0] + tv[1]*wr[1] + tv[2]*wr[2] + tv[3]*wr[3]
                     + tv[4]*wr[4] + tv[5]*wr[5] + tv[6]*wr[6] + tv[7]*wr[7];
        }
    }
    if (valid) {
        float* hp = h + (size_t)g * HID + cbase;
        #pragma unroll
        for (int c4 = 0; c4 < 4; ++c4) {
            float4 v;
            v.x = acc[c4*4+0] + bin2[cbase + c4*4+0];
            v.y = acc[c4*4+1] + bin2[cbase + c4*4+1];
            v.z = acc[c4*4+2] + bin2[cbase + c4*4+2];
            v.w = acc[c4*4+3] + bin2[cbase + c4*4+3];
            *(float4*)(hp + c4 * 4) = v;
        }
    }
}

// ===========================================================================
// k_mlp3: AB[n] = [h@Wa.T ; h@Wb.T] interleaved per node (128 floats/node).
// ===========================================================================
__global__ __launch_bounds__(256, 4) void k_mlp3(
    const float* __restrict__ h, const float* __restrict__ Wm1,
    float* __restrict__ AB)
{
    __shared__ float hsm[64 * 65];
    const int tid  = threadIdx.x;
    const int w    = __builtin_amdgcn_readfirstlane(tid >> 6);
    const int lane = tid & 63;
    const int node0 = blockIdx.x * 64;
    const int vcb = blockIdx.y * 32 + w * 8;
    const int which = vcb >> 6;
    const int cb = vcb & 63;
    const int g = min(node0 + lane, NN - 1);
    const bool valid = (node0 + lane) < NN;

    float acc[8];
    #pragma unroll
    for (int i = 0; i < 8; ++i) acc[i] = 0.f;

    for (int ch = 0; ch < 4; ++ch) {
        __syncthreads();
        for (int i = tid; i < 1024; i += 256) {
            int n = i >> 4, k4 = i & 15;
            int gr = min(node0 + n, NN - 1);
            float4 v = ((const float4*)h)[(size_t)gr * 64 + ch * 16 + k4];
            float* d = &hsm[n * 65 + k4 * 4];
            d[0] = v.x; d[1] = v.y; d[2] = v.z; d[3] = v.w;
        }
        __syncthreads();
        for (int kt = 0; kt < 8; ++kt) {
            float tv[8];
            #pragma unroll
            for (int i = 0; i < 8; ++i) tv[i] = hsm[lane * 65 + kt * 8 + i];
            #pragma unroll
            for (int jj = 0; jj < 8; ++jj) {
                const float* wr = Wm1 + (size_t)(cb + jj) * (2 * HID) + which * HID
                                + ch * 64 + kt * 8;
                acc[jj] += tv[0]*wr[0] + tv[1]*wr[1] + tv[2]*wr[2] + tv[3]*wr[3]
                         + tv[4]*wr[4] + tv[5]*wr[5] + tv[6]*wr[6] + tv[7]*wr[7];
            }
        }
    }
    if (valid) {
        float* dst = AB + (size_t)g * 128 + which * 64 + cb;
        float4 v0, v1;
        v0.x = acc[0]; v0.y = acc[1]; v0.z = acc[2]; v0.w = acc[3];
        v1.x = acc[4]; v1.y = acc[5]; v1.z = acc[6]; v1.w = acc[7];
        *(float4*)(dst + 0) = v0;
        *(float4*)(dst + 4) = v1;
    }
}

// ===========================================================================
// k_edge_msg — 64 edges/block. Writes P2 (bf16, CSR incidence order) twice
// per edge: normal orientation at src slot, TRANSPOSED at dst slot, so the
// sheaf gather is branch-free and addresses P sequentially.
// ===========================================================================
__global__ __launch_bounds__(256, 4) void k_edge_msg(
    const int* __restrict__ ei, const float* __restrict__ AB,
    const float* __restrict__ bm1, const float* __restrict__ Wm2, const float* __restrict__ bm2,
    unsigned short* __restrict__ P2,
    const int* __restrict__ posS, const int* __restrict__ posD,
    float* __restrict__ Qb, float* __restrict__ Rb)
{
    __shared__ float smem[128 * 64];
    __shared__ float wm2s[16 * 68];
    const int tid = threadIdx.x;
    const int w = tid >> 6, t = tid & 63;
    const int e0 = blockIdx.x * 64;

    for (int i = tid; i < 1024; i += 256)
        wm2s[(i >> 6) * 68 + (i & 63)] = Wm2[i];

    const float bm = bm1[t];
    const int tc = t >> 2, tr = t & 3;

    for (int r = 0; r < 16; ++r) {
        const int el = w * 16 + r;
        const int e = e0 + el;
        const int src = ei[e], dst = ei[EE + e];
        const float* su = AB + (size_t)src * 128;
        const float* du = AB + (size_t)dst * 128;
        float a_s = su[t];
        float b_s = su[64 + t];
        float a_d = du[t];
        float b_d = du[64 + t];
        const int row0 = el * 2, row1 = el * 2 + 1;
        smem[row0 * 64 + (((tc) + (row0 >> 2)) & 15) * 4 + tr] = fmaxf(a_s + b_d + bm, 0.f);
        smem[row1 * 64 + (((tc) + (row1 >> 2)) & 15) * 4 + tr] = fmaxf(a_d + b_s + bm, 0.f);
    }
    __syncthreads();

    float acc[4][2];
    {
        const int pg = tid & 31;
        const int jg = tid >> 5;
        const int j0 = jg * 2;
        #pragma unroll
        for (int i = 0; i < 4; ++i) { acc[i][0] = 0.f; acc[i][1] = 0.f; }

        const float4* w0 = (const float4*)&wm2s[(j0 + 0) * 68];
        const float4* w1 = (const float4*)&wm2s[(j0 + 1) * 68];
        const float4* p0 = (const float4*)&smem[(4 * pg + 0) * 64];
        const float4* p1 = (const float4*)&smem[(4 * pg + 1) * 64];
        const float4* p2 = (const float4*)&smem[(4 * pg + 2) * 64];
        const float4* p3 = (const float4*)&smem[(4 * pg + 3) * 64];

        #pragma unroll
        for (int k4 = 0; k4 < 16; ++k4) {
            const int ch = (k4 + pg) & 15;
            float4 wv0 = w0[k4], wv1 = w1[k4];
            float4 a = p0[ch], b = p1[ch], c = p2[ch], d = p3[ch];
            acc[0][0] += a.x*wv0.x + a.y*wv0.y + a.z*wv0.z + a.w*wv0.w;
            acc[0][1] += a.x*wv1.x + a.y*wv1.y + a.z*wv1.z + a.w*wv1.w;
            acc[1][0] += b.x*wv0.x + b.y*wv0.y + b.z*wv0.z + b.w*wv0.w;
            acc[1][1] += b.x*wv1.x + b.y*wv1.y + b.z*wv1.z + b.w*wv1.w;
            acc[2][0] += c.x*wv0.x + c.y*wv0.y + c.z*wv0.z + c.w*wv0.w;
            acc[2][1] += c.x*wv1.x + c.y*wv1.y + c.z*wv1.z + c.w*wv1.w;
            acc[3][0] += d.x*wv0.x + d.y*wv0.y + d.z*wv0.z + d.w*wv0.w;
            acc[3][1] += d.x*wv1.x + d.y*wv1.y + d.z*wv1.z + d.w*wv1.w;
        }
    }
    __syncthreads();

    float* fls = smem;
    {
        const int pg = tid & 31;
        const int jg = tid >> 5;
        const int j0 = jg * 2;
        float bm2a = bm2[j0], bm2b = bm2[j0 + 1];
        #pragma unroll
        for (int i = 0; i < 4; ++i) {
            fls[(4 * pg + i) * 17 + j0]     = acc[i][0] + bm2a;
            fls[(4 * pg + i) * 17 + j0 + 1] = acc[i][1] + bm2b;
        }
    }
    __syncthreads();

    {
        const int el = tid >> 2, cg = tid & 3;
        const float* f0 = &fls[(el * 2 + 0) * 17];
        const float* f1 = &fls[(el * 2 + 1) * 17];
        float a0 = f0[0*4+cg], a1 = f0[1*4+cg], a2 = f0[2*4+cg], a3 = f0[3*4+cg];
        float b0 = f1[0*4+cg], b1 = f1[1*4+cg], b2 = f1[2*4+cg], b3 = f1[3*4+cg];
        float4 pp, qq, rr;
        {
            float c0, c1, c2, c3;
            c0 = f1[0]; c1 = f1[4]; c2 = f1[8]; c3 = f1[12];
            pp.x = a0*c0 + a1*c1 + a2*c2 + a3*c3;
            rr.x = b0*c0 + b1*c1 + b2*c2 + b3*c3;
            c0 = f1[1]; c1 = f1[5]; c2 = f1[9]; c3 = f1[13];
            pp.y = a0*c0 + a1*c1 + a2*c2 + a3*c3;
            rr.y = b0*c0 + b1*c1 + b2*c2 + b3*c3;
            c0 = f1[2]; c1 = f1[6]; c2 = f1[10]; c3 = f1[14];
            pp.z = a0*c0 + a1*c1 + a2*c2 + a3*c3;
            rr.z = b0*c0 + b1*c1 + b2*c2 + b3*c3;
            c0 = f1[3]; c1 = f1[7]; c2 = f1[11]; c3 = f1[15];
            pp.w = a0*c0 + a1*c1 + a2*c2 + a3*c3;
            rr.w = b0*c0 + b1*c1 + b2*c2 + b3*c3;
            c0 = f0[0]; c1 = f0[4]; c2 = f0[8]; c3 = f0[12];
            qq.x = a0*c0 + a1*c1 + a2*c2 + a3*c3;
            c0 = f0[1]; c1 = f0[5]; c2 = f0[9]; c3 = f0[13];
            qq.y = a0*c0 + a1*c1 + a2*c2 + a3*c3;
            c0 = f0[2]; c1 = f0[6]; c2 = f0[10]; c3 = f0[14];
            qq.z = a0*c0 + a1*c1 + a2*c2 + a3*c3;
            c0 = f0[3]; c1 = f0[7]; c2 = f0[11]; c3 = f0[15];
            qq.w = a0*c0 + a1*c1 + a2*c2 + a3*c3;
        }
        const int eg = e0 + el;
        const int pS = posS[eg];
        const int pD = posD[eg];
        // src slot: row-major (lane cg writes row cg = 8B contiguous)
        unsigned sx = (unsigned)f2bf(pp.x) | ((unsigned)f2bf(pp.y) << 16);
        unsigned sy = (unsigned)f2bf(pp.z) | ((unsigned)f2bf(pp.w) << 16);
        *(uint2*)(P2 + (size_t)pS * 16 + cg * 4) = make_uint2(sx, sy);
        // dst slot: transposed (element (j,cg) = pp[j])
        unsigned short* rowD = P2 + (size_t)pD * 16;
        rowD[0 * 4 + cg] = f2bf(pp.x);
        rowD[1 * 4 + cg] = f2bf(pp.y);
        rowD[2 * 4 + cg] = f2bf(pp.z);
        rowD[3 * 4 + cg] = f2bf(pp.w);
        *(float4*)(Qb + (size_t)eg * 16 + cg * 4) = qq;
        *(float4*)(Rb + (size_t)eg * 16 + cg * 4) = rr;
    }
}

// ===========================================================================
// k_nodeM — M[n] = Σ Qb (src-inc) + Σ Rb (dst-inc) via CSR, no atomics.
// ===========================================================================
__global__ __launch_bounds__(256) void k_nodeM(
    const int* __restrict__ inc, const int* __restrict__ off,
    const float* __restrict__ Qb, const float* __restrict__ Rb,
    float* __restrict__ M)
{
    const int tid = threadIdx.x;
    const int ni = tid >> 4, comp = tid & 15;
    const int n = blockIdx.x * 16 + ni;
    const int p0 = off[n], p1 = off[n + 1];
    float s = 0.f;
    for (int p = p0; p < p1; ++p) {
        int v = inc[p];
        const float* src = (v & 1) ? Rb : Qb;
        s += src[(size_t)(v >> 1) * 16 + comp];
    }
    M[(size_t)n * 16 + comp] = s;
}

// ===========================================================================
// k_node_H — H0 = (Wd1.T @ xb) @ Wd2.T per node, stored as BF16 (packed
// per-lane layout H[n][t*4+k]). Wd2 read directly from global.
// ===========================================================================
__global__ __launch_bounds__(256) void k_node_H(
    const float* __restrict__ xb,
    const float* __restrict__ Wd1l, const float* __restrict__ Wd2l,
    unsigned short* __restrict__ H)
{
    __shared__ float tl[4][4][64];
    const int tid = threadIdx.x;
    const int w = __builtin_amdgcn_readfirstlane(tid >> 6);
    const int t = tid & 63;

    float wd1[16];
    #pragma unroll
    for (int i = 0; i < 16; ++i) wd1[i] = Wd1l[i];
    const float* wrow = Wd2l + t * 64;

    for (int rep = 0; rep < 4; ++rep) {
        const int n = blockIdx.x * 16 + w * 4 + rep;
        float xv[4];
        #pragma unroll
        for (int j = 0; j < 4; ++j) xv[j] = xb[(size_t)n * HID + j * 64 + t];
        #pragma unroll
        for (int i = 0; i < 4; ++i)
            tl[w][i][t] = wd1[0 + i] * xv[0] + wd1[4 + i] * xv[1] +
                          wd1[8 + i] * xv[2] + wd1[12 + i] * xv[3];
        float a0 = 0, a1 = 0, a2 = 0, a3 = 0;
        #pragma unroll
        for (int f = 0; f < 64; f += 4) {
            float4 wv = *(const float4*)(wrow + f);
            float4 t0 = *(const float4*)&tl[w][0][f];
            float4 t1 = *(const float4*)&tl[w][1][f];
            float4 t2 = *(const float4*)&tl[w][2][f];
            float4 t3 = *(const float4*)&tl[w][3][f];
            a0 += t0.x * wv.x + t0.y * wv.y + t0.z * wv.z + t0.w * wv.w;
            a1 += t1.x * wv.x + t1.y * wv.y + t1.z * wv.z + t1.w * wv.w;
            a2 += t2.x * wv.x + t2.y * wv.y + t2.z * wv.z + t2.w * wv.w;
            a3 += t3.x * wv.x + t3.y * wv.y + t3.z * wv.z + t3.w * wv.w;
        }
        unsigned lo = (unsigned)f2bf(a0) | ((unsigned)f2bf(a1) << 16);
        unsigned hi = (unsigned)f2bf(a2) | ((unsigned)f2bf(a3) << 16);
        *(uint2*)(H + (size_t)n * HID + (t << 2)) = make_uint2(lo, hi);
    }
}

// ===========================================================================
// sheaf gather v4 — ALL scalar streams have statically-known sequential
// addresses (inc2[p] and P2 row p); the only dependent load is H. P2 is
// bf16 CSR-ordered pre-transposed: branch-free apply, wave-uniform unpack
// (SALU shifts feeding one-SGPR-operand FMAs).
// ===========================================================================
__device__ __forceinline__ void sheaf_apply_bf(const unsigned pr[8], uint2 u, float acc[4])
{
    const float h0 = __uint_as_float(u.x << 16);
    const float h1 = __uint_as_float(u.x & 0xFFFF0000u);
    const float h2 = __uint_as_float(u.y << 16);
    const float h3 = __uint_as_float(u.y & 0xFFFF0000u);
    #pragma unroll
    for (int j = 0; j < 4; ++j) {
        const unsigned d0 = pr[j * 2 + 0], d1 = pr[j * 2 + 1];
        const float q0 = __uint_as_float(d0 << 16);
        const float q1 = __uint_as_float(d0 & 0xFFFF0000u);
        const float q2 = __uint_as_float(d1 << 16);
        const float q3 = __uint_as_float(d1 & 0xFFFF0000u);
        acc[j] -= q0 * h0 + q1 * h1 + q2 * h2 + q3 * h3;
    }
}

__device__ __forceinline__ void sheaf_gather(
    const int* __restrict__ inc2,
    const unsigned short* __restrict__ P2, const unsigned short* __restrict__ Hin,
    int p0, int p1, int t, float acc[4])
{
    int p = p0;
    for (; p + 2 <= p1; p += 2) {
        const int oA = __builtin_amdgcn_readfirstlane(inc2[p]);
        const int oB = __builtin_amdgcn_readfirstlane(inc2[p + 1]);
        const uint2 uA = *(const uint2*)(Hin + (size_t)oA * HID + (t << 2));
        const uint2 uB = *(const uint2*)(Hin + (size_t)oB * HID + (t << 2));
        const unsigned* pr = (const unsigned*)P2 + (size_t)p * 8;
        unsigned da[8], db[8];
        #pragma unroll
        for (int i = 0; i < 8; ++i) da[i] = pr[i];
        #pragma unroll
        for (int i = 0; i < 8; ++i) db[i] = pr[8 + i];
        sheaf_apply_bf(da, uA, acc);
        sheaf_apply_bf(db, uB, acc);
    }
    if (p < p1) {
        const int o = __builtin_amdgcn_readfirstlane(inc2[p]);
        const uint2 u = *(const uint2*)(Hin + (size_t)o * HID + (t << 2));
        const unsigned* pr = (const unsigned*)P2 + (size_t)p * 8;
        unsigned da[8];
        #pragma unroll
        for (int i = 0; i < 8; ++i) da[i] = pr[i];
        sheaf_apply_bf(da, u, acc);
    }
}

// ===========================================================================
// k_sheaf0 — layer 0: LH gather + xb update + fused next-layer H (bf16 out).
// Wd2 from global (L2-resident); LDS = tl only (4 KB); barrier-free.
// ===========================================================================
__global__ __launch_bounds__(256) void k_sheaf0(
    const int* __restrict__ inc2, const int* __restrict__ off,
    const unsigned short* __restrict__ P2, const float* __restrict__ M,
    const unsigned short* __restrict__ Hin, float* __restrict__ h,
    unsigned short* __restrict__ Hout,
    const float* __restrict__ Wd1l, const float* __restrict__ Wd2l)
{
    __shared__ float tl[4][4][64];
    const int tid = threadIdx.x;
    const int w = __builtin_amdgcn_readfirstlane(tid >> 6);
    const int t = tid & 63;

    float wd1[16];
    #pragma unroll
    for (int i = 0; i < 16; ++i) wd1[i] = Wd1l[i];

    const int n = blockIdx.x * 4 + w;
    const uint2 un = *(const uint2*)(Hin + (size_t)n * HID + (t << 2));
    float Hn[4];
    Hn[0] = __uint_as_float(un.x << 16);
    Hn[1] = __uint_as_float(un.x & 0xFFFF0000u);
    Hn[2] = __uint_as_float(un.y << 16);
    Hn[3] = __uint_as_float(un.y & 0xFFFF0000u);
    float Mn[16];
    #pragma unroll
    for (int c = 0; c < 16; ++c) Mn[c] = M[(size_t)n * 16 + c];

    float acc[4];
    #pragma unroll
    for (int j = 0; j < 4; ++j)
        acc[j] = Mn[j*4+0]*Hn[0] + Mn[j*4+1]*Hn[1] + Mn[j*4+2]*Hn[2] + Mn[j*4+3]*Hn[3];

    const int p0 = __builtin_amdgcn_readfirstlane(off[n]);
    const int p1 = __builtin_amdgcn_readfirstlane(off[n + 1]);
    sheaf_gather(inc2, P2, Hin, p0, p1, t, acc);

    float xv[4];
    #pragma unroll
    for (int j = 0; j < 4; ++j) {
        size_t idx = (size_t)n * HID + j * 64 + t;
        float vv = h[idx] - fmaxf(acc[j], 0.f);
        h[idx] = vv;
        xv[j] = vv;
    }

    #pragma unroll
    for (int i = 0; i < 4; ++i)
        tl[w][i][t] = wd1[0 + i] * xv[0] + wd1[4 + i] * xv[1] +
                      wd1[8 + i] * xv[2] + wd1[12 + i] * xv[3];
    // no __syncthreads(): tl[w] is wave-private; DS ops complete in order.
    const float* wrow = Wd2l + t * 64;
    float a0 = 0, a1 = 0, a2 = 0, a3 = 0;
    #pragma unroll
    for (int f = 0; f < 64; f += 4) {
        float4 wv = *(const float4*)(wrow + f);
        float4 t0 = *(const float4*)&tl[w][0][f];
        float4 t1 = *(const float4*)&tl[w][1][f];
        float4 t2 = *(const float4*)&tl[w][2][f];
        float4 t3 = *(const float4*)&tl[w][3][f];
        a0 += t0.x * wv.x + t0.y * wv.y + t0.z * wv.z + t0.w * wv.w;
        a1 += t1.x * wv.x + t1.y * wv.y + t1.z * wv.z + t1.w * wv.w;
        a2 += t2.x * wv.x + t2.y * wv.y + t2.z * wv.z + t2.w * wv.w;
        a3 += t3.x * wv.x + t3.y * wv.y + t3.z * wv.z + t3.w * wv.w;
    }
    unsigned lo = (unsigned)f2bf(a0) | ((unsigned)f2bf(a1) << 16);
    unsigned hi = (unsigned)f2bf(a2) | ((unsigned)f2bf(a3) << 16);
    *(uint2*)(Hout + (size_t)n * HID + (t << 2)) = make_uint2(lo, hi);
}

// ===========================================================================
// k_sheaf1 — layer 1: LH gather + xb update only. ZERO LDS.
// ===========================================================================
__global__ __launch_bounds__(256) void k_sheaf1(
    const int* __restrict__ inc2, const int* __restrict__ off,
    const unsigned short* __restrict__ P2, const float* __restrict__ M,
    const unsigned short* __restrict__ Hin, float* __restrict__ h)
{
    const int tid = threadIdx.x;
    const int w = __builtin_amdgcn_readfirstlane(tid >> 6);
    const int t = tid & 63;
    const int n = blockIdx.x * 4 + w;

    const uint2 un = *(const uint2*)(Hin + (size_t)n * HID + (t << 2));
    float Hn[4];
    Hn[0] = __uint_as_float(un.x << 16);
    Hn[1] = __uint_as_float(un.x & 0xFFFF0000u);
    Hn[2] = __uint_as_float(un.y << 16);
    Hn[3] = __uint_as_float(un.y & 0xFFFF0000u);
    float Mn[16];
    #pragma unroll
    for (int c = 0; c < 16; ++c) Mn[c] = M[(size_t)n * 16 + c];

    float acc[4];
    #pragma unroll
    for (int j = 0; j < 4; ++j)
        acc[j] = Mn[j*4+0]*Hn[0] + Mn[j*4+1]*Hn[1] + Mn[j*4+2]*Hn[2] + Mn[j*4+3]*Hn[3];

    const int p0 = __builtin_amdgcn_readfirstlane(off[n]);
    const int p1 = __builtin_amdgcn_readfirstlane(off[n + 1]);
    sheaf_gather(inc2, P2, Hin, p0, p1, t, acc);

    #pragma unroll
    for (int j = 0; j < 4; ++j) {
        size_t idx = (size_t)n * HID + j * 64 + t;
        h[idx] = h[idx] - fmaxf(acc[j], 0.f);
    }
}

// ===========================================================================
// k_out1: t1o = relu(xb @ Wo1.T + bo1).  grid (N/64, 4).
// ===========================================================================
__global__ __launch_bounds__(256, 4) void k_out1(
    const float* __restrict__ xb, const float* __restrict__ Wo1, const float* __restrict__ bo1,
    float* __restrict__ t1o)
{
    __shared__ float xr[64 * 129];
    const int tid  = threadIdx.x;
    const int w    = __builtin_amdgcn_readfirstlane(tid >> 6);
    const int lane = tid & 63;
    const int node0 = blockIdx.x * 64;
    const int cbase = blockIdx.y * 16 + w * 4;
    const int g = min(node0 + lane, NN - 1);
    const bool valid = (node0 + lane) < NN;

    float acc[4] = {0.f, 0.f, 0.f, 0.f};

    for (int j = 0; j < 2; ++j) {
        __syncthreads();
        for (int i = tid; i < 2048; i += 256) {
            int n = i >> 5, k4 = i & 31;
            int gr = min(node0 + n, NN - 1);
            float4 v = ((const float4*)xb)[(size_t)gr * 64 + j * 32 + k4];
            float* d = &xr[n * 129 + k4 * 4];
            d[0] = v.x; d[1] = v.y; d[2] = v.z; d[3] = v.w;
        }
        __syncthreads();
        for (int kt = 0; kt < 32; ++kt) {
            float x0 = xr[lane * 129 + kt * 4 + 0];
            float x1 = xr[lane * 129 + kt * 4 + 1];
            float x2 = xr[lane * 129 + kt * 4 + 2];
            float x3 = xr[lane * 129 + kt * 4 + 3];
            #pragma unroll
            for (int cc = 0; cc < 4; ++cc) {
                const float* wr = Wo1 + (size_t)(cbase + cc) * HID + j * 128 + kt * 4;
                acc[cc] += x0 * wr[0] + x1 * wr[1] + x2 * wr[2] + x3 * wr[3];
            }
        }
    }
    if (valid) {
        float4 v;
        v.x = fmaxf(acc[0] + bo1[cbase + 0], 0.f);
        v.y = fmaxf(acc[1] + bo1[cbase + 1], 0.f);
        v.z = fmaxf(acc[2] + bo1[cbase + 2], 0.f);
        v.w = fmaxf(acc[3] + bo1[cbase + 3], 0.f);
        *(float4*)(t1o + (size_t)g * MH + cbase) = v;
    }
}

// ===========================================================================
// k_out2: out = t1o @ Wo2.T + bo2.
// ===========================================================================
__global__ __launch_bounds__(256, 4) void k_out2(
    const float* __restrict__ t1o, const float* __restrict__ Wo2, const float* __restrict__ bo2,
    float* __restrict__ out)
{
    __shared__ float ts[64 * 65];
    const int tid  = threadIdx.x;
    const int lane = tid & 63;
    const int node0 = blockIdx.x * 64;
    const int g = min(node0 + lane, NN - 1);
    const bool valid = (node0 + lane) < NN;

    for (int i = tid; i < 1024; i += 256) {
        int n = i >> 4, k4 = i & 15;
        int gr = min(node0 + n, NN - 1);
        float4 v = ((const float4*)t1o)[(size_t)gr * 16 + k4];
        float* d = &ts[n * 65 + k4 * 4];
        d[0] = v.x; d[1] = v.y; d[2] = v.z; d[3] = v.w;
    }
    __syncthreads();

    float acc[16];
    #pragma unroll
    for (int i = 0; i < 16; ++i) acc[i] = 0.f;
    for (int kt = 0; kt < 8; ++kt) {
        float tv[8];
        #pragma unroll
        for (int i = 0; i < 8; ++i) tv[i] = ts[lane * 65 + kt * 8 + i];
        #pragma unroll
        for (int jj = 0; jj < 16; ++jj) {
            const float* wr = Wo2 + (size_t)jj * MH + kt * 8;
            acc[jj] += tv[0]*wr[0] + tv[1]*wr[1] + tv[2]*wr[2] + tv[3]*wr[3]
                     + tv[4]*wr[4] + tv[5]*wr[5] + tv[6]*wr[6] + tv[7]*wr[7];
        }
    }
    if (valid) {
        float* op = out + (size_t)g * OUT_D;
        #pragma unroll
        for (int c4 = 0; c4 < 4; ++c4) {
            float4 v;
            v.x = acc[c4*4+0] + bo2[c4*4+0];
            v.y = acc[c4*4+1] + bo2[c4*4+1];
            v.z = acc[c4*4+2] + bo2[c4*4+2];
            v.w = acc[c4*4+3] + bo2[c4*4+3];
            *(float4*)(op + c4 * 4) = v;
        }
    }
}

// ---------------------------------------------------------------------------
// Workspace (~89.2 MB, unchanged total). P2 (bf16, 2E*16*2B = 12.8MB)
// occupies the old f32 P region exactly. posS/posD (1.6MB) parked in the
// dead tail of H1 (beyond Rb's 12.8MB; H1b later uses only first 10.24MB).
// ---------------------------------------------------------------------------
extern "C" void kernel_launch(void* const* d_in, const int* in_sizes, int n_in,
                              void* d_out, int out_size, void* d_ws, size_t ws_size,
                              hipStream_t stream)
{
    const float* x    = (const float*)d_in[0];
    const int*   ei   = (const int*)d_in[1];
    const float* Win1 = (const float*)d_in[2];
    const float* bin1 = (const float*)d_in[3];
    const float* Win2 = (const float*)d_in[4];
    const float* bin2 = (const float*)d_in[5];
    const float* Wm1  = (const float*)d_in[6];
    const float* bm1  = (const float*)d_in[7];
    const float* Wm2  = (const float*)d_in[8];
    const float* bm2  = (const float*)d_in[9];
    const float* Wd1  = (const float*)d_in[10];
    const float* Wd2  = (const float*)d_in[11];
    const float* Wo1  = (const float*)d_in[12];
    const float* bo1  = (const float*)d_in[13];
    const float* Wo2  = (const float*)d_in[14];
    const float* bo2  = (const float*)d_in[15];
    float* out = (float*)d_out;

    float* ws = (float*)d_ws;
    float* h  = ws;                            // N*256
    float* AB = h  + (size_t)NN * HID;         // N*128 (interleaved A|B)
    float* H0 = AB + (size_t)NN * 128;         // N*256 region
    float* H1 = H0 + (size_t)NN * HID;         // N*256 region
    float* Pf = H1 + (size_t)NN * HID;         // E*16 f32 region -> bf16 P2
    float* M  = Pf + (size_t)EE * 16;          // N*16
    int* deg    = (int*)(M + (size_t)NN * 16); // N
    int* off    = deg + NN;                    // N+1
    int* cursor = off + NN + 1;                // N
    int* inc    = cursor + NN;                 // 2E
    int* inc2   = inc + 2 * EE;                // 2E
    float* t1  = H0;                           // alias
    float* t1o = H1;                           // alias
    float* Qb  = H0;                           // alias
    float* Rb  = H1;                           // alias
    unsigned short* H0b = (unsigned short*)H0; // bf16 view (first half)
    unsigned short* H1b = (unsigned short*)H1;
    unsigned short* P2  = (unsigned short*)Pf; // bf16 CSR-ordered P (2E*16)
    int* bsum = (int*)H1;                      // 250 ints, dead at scan time
    int* posS = (int*)(H1 + 3500000);          // E ints @ H1+14MB (dead tail)
    int* posD = posS + EE;                     // E ints

    const int NB = (NN + 63) / 64;             // 313

    // CSR build (parallel scan: 250x80 local -> 1-block top -> add base)
    hipMemsetAsync(deg, 0, NN * sizeof(int), stream);
    k_deg<<<(EE + 255) / 256, 256, 0, stream>>>(ei, deg);
    k_scan_a<<<250, 128, 0, stream>>>(deg, off, bsum);
    k_scan_b<<<1, 256, 0, stream>>>(bsum);
    k_scan_c<<<(NN + 255) / 256, 256, 0, stream>>>(bsum, off, cursor);
    k_scatter<<<(EE + 255) / 256, 256, 0, stream>>>(ei, cursor, inc, inc2, posS, posD);

    // node MLP + per-edge P2/Q/R (no atomics) + CSR-gathered M
    k_mlp1<<<dim3(NB, 4), 256, 0, stream>>>(x, Win1, bin1, t1);
    k_mlp2<<<dim3(NB, 4), 256, 0, stream>>>(t1, Win2, bin2, h);
    k_mlp3<<<dim3(NB, 4), 256, 0, stream>>>(h, Wm1, AB);
    k_edge_msg<<<EE / 64, 256, 0, stream>>>(ei, AB, bm1, Wm2, bm2, P2, posS, posD, Qb, Rb);
    k_nodeM<<<NN / 16, 256, 0, stream>>>(inc, off, Qb, Rb, M);

    // diffusion (H in bf16 packed per-lane layout; P2 bf16 CSR-ordered)
    k_node_H<<<NN / 16, 256, 0, stream>>>(h, Wd1, Wd2, H0b);
    k_sheaf0<<<NN / 4, 256, 0, stream>>>(inc2, off, P2, M, H0b, h, H1b,
                                         Wd1 + 16, Wd2 + 4096);
    k_sheaf1<<<NN / 4, 256, 0, stream>>>(inc2, off, P2, M, H1b, h);

    // output MLP
    k_out1<<<dim3(NB, 4), 256, 0, stream>>>(h, Wo1, bo1, t1o);
    k_out2<<<NB, 256, 0, stream>>>(t1o, Wo2, bo2, out);
}

// Round 9
// 454.568 us; speedup vs baseline: 2.5561x; 1.0388x over previous
//
#include <hip/hip_runtime.h>

constexpr int NN   = 20000;
constexpr int EE   = 200000;
constexpr int IN_D = 500;
constexpr int HID  = 256;
constexpr int OUT_D= 16;
constexpr int MH   = 64;

// bf16 helpers (internal H/P/AB storage only)
__device__ __forceinline__ float bf2f(unsigned short s) {
    return __uint_as_float((unsigned)s << 16);
}
__device__ __forceinline__ unsigned short f2bf(float f) {
    unsigned u = __float_as_uint(f);
    unsigned r = u + 0x7FFF + ((u >> 16) & 1);   // round-to-nearest-even
    return (unsigned short)(r >> 16);
}

// ===========================================================================
// CSR incidence build. inc2 entry = other node. posS/posD record each edge's
// two CSR slots (for CSR-ordered P2 and QR2). No inc array needed anymore.
// ===========================================================================
__global__ __launch_bounds__(256) void k_deg(const int* __restrict__ ei, int* __restrict__ deg)
{
    int e = blockIdx.x * 256 + threadIdx.x;
    if (e < EE) {
        atomicAdd(deg + ei[e], 1);
        atomicAdd(deg + ei[EE + e], 1);
    }
}

// Parallel scan, 3 kernels. Block sums parked in dead H1 region.
__global__ __launch_bounds__(128) void k_scan_a(const int* __restrict__ deg,
                                                int* __restrict__ off, int* __restrict__ bsum)
{
    __shared__ int s[128];
    const int b = blockIdx.x, tid = threadIdx.x;
    const int n = b * 80 + tid;
    int v = (tid < 80) ? deg[n] : 0;
    s[tid] = v;
    __syncthreads();
    for (int o = 1; o < 128; o <<= 1) {
        int x = 0;
        if (tid >= o) x = s[tid - o];
        __syncthreads();
        if (tid >= o) s[tid] += x;
        __syncthreads();
    }
    if (tid < 80) off[n] = s[tid] - v;     // local exclusive prefix
    if (tid == 127) bsum[b] = s[127];      // block total
}

__global__ __launch_bounds__(256) void k_scan_b(int* __restrict__ bsum)
{
    __shared__ int s[256];
    const int tid = threadIdx.x;
    int v = (tid < 250) ? bsum[tid] : 0;
    s[tid] = v;
    __syncthreads();
    for (int o = 1; o < 256; o <<= 1) {
        int x = 0;
        if (tid >= o) x = s[tid - o];
        __syncthreads();
        if (tid >= o) s[tid] += x;
        __syncthreads();
    }
    if (tid < 250) bsum[tid] = s[tid] - v; // exclusive
}

__global__ __launch_bounds__(256) void k_scan_c(const int* __restrict__ bsum,
                                                int* __restrict__ off, int* __restrict__ cursor)
{
    const int n = blockIdx.x * 256 + threadIdx.x;
    if (n < NN) {
        int o = off[n] + bsum[n / 80];
        off[n] = o;
        cursor[n] = o;
    }
    if (n == 0) off[NN] = 2 * EE;
}

__global__ __launch_bounds__(256) void k_scatter(const int* __restrict__ ei,
                                                 int* __restrict__ cursor,
                                                 int* __restrict__ inc2,
                                                 int* __restrict__ posS, int* __restrict__ posD)
{
    int e = blockIdx.x * 256 + threadIdx.x;
    if (e < EE) {
        int s = ei[e], d = ei[EE + e];
        int p = atomicAdd(cursor + s, 1); inc2[p] = d; posS[e] = p;
        p = atomicAdd(cursor + d, 1);     inc2[p] = s; posD[e] = p;
    }
}

// ===========================================================================
// k_mlp1: t1 = relu(x @ Win1.T + bin1).  grid (N/64, 4).
// Wave-uniform weight rows -> scalar-pipe weight loads.
// ===========================================================================
__global__ __launch_bounds__(256, 4) void k_mlp1(
    const float* __restrict__ x, const float* __restrict__ Win1, const float* __restrict__ bin1,
    float* __restrict__ t1)
{
    __shared__ float xs[64 * 101];
    const int tid  = threadIdx.x;
    const int w    = __builtin_amdgcn_readfirstlane(tid >> 6);
    const int lane = tid & 63;
    const int node0 = blockIdx.x * 64;
    const int cbase = blockIdx.y * 16 + w * 4;
    const int g = min(node0 + lane, NN - 1);
    const bool valid = (node0 + lane) < NN;

    float acc[4] = {0.f, 0.f, 0.f, 0.f};

    for (int j = 0; j < 5; ++j) {
        __syncthreads();
        for (int i = tid; i < 1600; i += 256) {
            int n = i / 25, k4 = i % 25;
            int gr = min(node0 + n, NN - 1);
            float4 v = ((const float4*)x)[(size_t)gr * 125 + j * 25 + k4];
            float* d = &xs[n * 101 + k4 * 4];
            d[0] = v.x; d[1] = v.y; d[2] = v.z; d[3] = v.w;
        }
        __syncthreads();
        for (int kt = 0; kt < 25; ++kt) {
            float x0 = xs[lane * 101 + kt * 4 + 0];
            float x1 = xs[lane * 101 + kt * 4 + 1];
            float x2 = xs[lane * 101 + kt * 4 + 2];
            float x3 = xs[lane * 101 + kt * 4 + 3];
            #pragma unroll
            for (int cc = 0; cc < 4; ++cc) {
                const float* wr = Win1 + (size_t)(cbase + cc) * IN_D + j * 100 + kt * 4;
                acc[cc] += x0 * wr[0] + x1 * wr[1] + x2 * wr[2] + x3 * wr[3];
            }
        }
    }
    if (valid) {
        float4 v;
        v.x = fmaxf(acc[0] + bin1[cbase + 0], 0.f);
        v.y = fmaxf(acc[1] + bin1[cbase + 1], 0.f);
        v.z = fmaxf(acc[2] + bin1[cbase + 2], 0.f);
        v.w = fmaxf(acc[3] + bin1[cbase + 3], 0.f);
        *(float4*)(t1 + (size_t)g * MH + cbase) = v;
    }
}

// ===========================================================================
// k_mlp2: h = t1 @ Win2.T + bin2.  grid (N/64, 4).
// ===========================================================================
__global__ __launch_bounds__(256, 4) void k_mlp2(
    const float* __restrict__ t1, const float* __restrict__ Win2, const float* __restrict__ bin2,
    float* __restrict__ h)
{
    __shared__ float ts[64 * 65];
    const int tid  = threadIdx.x;
    const int w    = __builtin_amdgcn_readfirstlane(tid >> 6);
    const int lane = tid & 63;
    const int node0 = blockIdx.x * 64;
    const int cbase = blockIdx.y * 64 + w * 16;
    const int g = min(node0 + lane, NN - 1);
    const bool valid = (node0 + lane) < NN;

    for (int i = tid; i < 1024; i += 256) {
        int n = i >> 4, k4 = i & 15;
        int gr = min(node0 + n, NN - 1);
        float4 v = ((const float4*)t1)[(size_t)gr * 16 + k4];
        float* d = &ts[n * 65 + k4 * 4];
        d[0] = v.x; d[1] = v.y; d[2] = v.z; d[3] = v.w;
    }
    __syncthreads();

    float acc[16];
    #pragma unroll
    for (int i = 0; i < 16; ++i) acc[i] = 0.f;
    for (int kt = 0; kt < 8; ++kt) {
        float tv[8];
        #pragma unroll
        for (int i = 0; i < 8; ++i) tv[i] = ts[lane * 65 + kt * 8 + i];
        #pragma unroll
        for (int cc = 0; cc < 16; ++cc) {
            const float* wr = Win2 + (size_t)(cbase + cc) * MH + kt * 8;
            acc[cc] += tv[0]*wr[0] + tv[1]*wr[1] + tv[2]*wr[2] + tv[3]*wr[3]
                     + tv[4]*wr[4] + tv[5]*wr[5] + tv[6]*wr[6] + tv[7]*wr[7];
        }
    }
    if (valid) {
        float* hp = h + (size_t)g * HID + cbase;
        #pragma unroll
        for (int c4 = 0; c4 < 4; ++c4) {
            float4 v;
            v.x = acc[c4*4+0] + bin2[cbase + c4*4+0];
            v.y = acc[c4*4+1] + bin2[cbase + c4*4+1];
            v.z = acc[c4*4+2] + bin2[cbase + c4*4+2];
            v.w = acc[c4*4+3] + bin2[cbase + c4*4+3];
            *(float4*)(hp + c4 * 4) = v;
        }
    }
}

// ===========================================================================
// k_mlp3: AB2[n][c] = {bf16 a_c, bf16 b_c} packed per dword. Each thread
// computes a[c] AND b[c] for 4 channels (same total FLOPs; both weight rows
// wave-uniform). grid (N/64, 4): cb = (y*4+w)*4 covers c=0..63.
// ===========================================================================
__global__ __launch_bounds__(256, 4) void k_mlp3(
    const float* __restrict__ h, const float* __restrict__ Wm1,
    unsigned* __restrict__ AB2)
{
    __shared__ float hsm[64 * 65];
    const int tid  = threadIdx.x;
    const int w    = __builtin_amdgcn_readfirstlane(tid >> 6);
    const int lane = tid & 63;
    const int node0 = blockIdx.x * 64;
    const int cb = (blockIdx.y * 4 + w) * 4;   // channel base, 0..60
    const int g = min(node0 + lane, NN - 1);
    const bool valid = (node0 + lane) < NN;

    float accA[4], accB[4];
    #pragma unroll
    for (int i = 0; i < 4; ++i) { accA[i] = 0.f; accB[i] = 0.f; }

    for (int ch = 0; ch < 4; ++ch) {
        __syncthreads();
        for (int i = tid; i < 1024; i += 256) {
            int n = i >> 4, k4 = i & 15;
            int gr = min(node0 + n, NN - 1);
            float4 v = ((const float4*)h)[(size_t)gr * 64 + ch * 16 + k4];
            float* d = &hsm[n * 65 + k4 * 4];
            d[0] = v.x; d[1] = v.y; d[2] = v.z; d[3] = v.w;
        }
        __syncthreads();
        for (int kt = 0; kt < 8; ++kt) {
            float tv[8];
            #pragma unroll
            for (int i = 0; i < 8; ++i) tv[i] = hsm[lane * 65 + kt * 8 + i];
            #pragma unroll
            for (int cc = 0; cc < 4; ++cc) {
                const float* wrA = Wm1 + (size_t)(cb + cc) * (2 * HID) + ch * 64 + kt * 8;
                const float* wrB = wrA + HID;
                accA[cc] += tv[0]*wrA[0] + tv[1]*wrA[1] + tv[2]*wrA[2] + tv[3]*wrA[3]
                          + tv[4]*wrA[4] + tv[5]*wrA[5] + tv[6]*wrA[6] + tv[7]*wrA[7];
                accB[cc] += tv[0]*wrB[0] + tv[1]*wrB[1] + tv[2]*wrB[2] + tv[3]*wrB[3]
                          + tv[4]*wrB[4] + tv[5]*wrB[5] + tv[6]*wrB[6] + tv[7]*wrB[7];
            }
        }
    }
    if (valid) {
        uint4 pk;
        pk.x = (unsigned)f2bf(accA[0]) | ((unsigned)f2bf(accB[0]) << 16);
        pk.y = (unsigned)f2bf(accA[1]) | ((unsigned)f2bf(accB[1]) << 16);
        pk.z = (unsigned)f2bf(accA[2]) | ((unsigned)f2bf(accB[2]) << 16);
        pk.w = (unsigned)f2bf(accA[3]) | ((unsigned)f2bf(accB[3]) << 16);
        *(uint4*)(AB2 + (size_t)g * 64 + cb) = pk;
    }
}

// ===========================================================================
// k_edge_msg — 64 edges/block. AB2 packed gather: ONE dword per lane per
// endpoint gives both a and b. Writes P2 (bf16, CSR order, transposed at the
// dst slot) and QR2 (f32, CSR order -> k_nodeM is a sequential reduction).
// ===========================================================================
__global__ __launch_bounds__(256, 4) void k_edge_msg(
    const int* __restrict__ ei, const unsigned* __restrict__ AB2,
    const float* __restrict__ bm1, const float* __restrict__ Wm2, const float* __restrict__ bm2,
    unsigned short* __restrict__ P2,
    const int* __restrict__ posS, const int* __restrict__ posD,
    float* __restrict__ QR2)
{
    __shared__ float smem[128 * 64];
    __shared__ float wm2s[16 * 68];
    const int tid = threadIdx.x;
    const int w = tid >> 6, t = tid & 63;
    const int e0 = blockIdx.x * 64;

    for (int i = tid; i < 1024; i += 256)
        wm2s[(i >> 6) * 68 + (i & 63)] = Wm2[i];

    const float bm = bm1[t];
    const int tc = t >> 2, tr = t & 3;

    for (int r = 0; r < 16; ++r) {
        const int el = w * 16 + r;
        const int e = e0 + el;
        const int src = ei[e], dst = ei[EE + e];
        const unsigned pk_s = AB2[(size_t)src * 64 + t];
        const unsigned pk_d = AB2[(size_t)dst * 64 + t];
        const float a_s = __uint_as_float(pk_s << 16);
        const float b_s = __uint_as_float(pk_s & 0xFFFF0000u);
        const float a_d = __uint_as_float(pk_d << 16);
        const float b_d = __uint_as_float(pk_d & 0xFFFF0000u);
        const int row0 = el * 2, row1 = el * 2 + 1;
        smem[row0 * 64 + (((tc) + (row0 >> 2)) & 15) * 4 + tr] = fmaxf(a_s + b_d + bm, 0.f);
        smem[row1 * 64 + (((tc) + (row1 >> 2)) & 15) * 4 + tr] = fmaxf(a_d + b_s + bm, 0.f);
    }
    __syncthreads();

    float acc[4][2];
    {
        const int pg = tid & 31;
        const int jg = tid >> 5;
        const int j0 = jg * 2;
        #pragma unroll
        for (int i = 0; i < 4; ++i) { acc[i][0] = 0.f; acc[i][1] = 0.f; }

        const float4* w0 = (const float4*)&wm2s[(j0 + 0) * 68];
        const float4* w1 = (const float4*)&wm2s[(j0 + 1) * 68];
        const float4* p0 = (const float4*)&smem[(4 * pg + 0) * 64];
        const float4* p1 = (const float4*)&smem[(4 * pg + 1) * 64];
        const float4* p2 = (const float4*)&smem[(4 * pg + 2) * 64];
        const float4* p3 = (const float4*)&smem[(4 * pg + 3) * 64];

        #pragma unroll
        for (int k4 = 0; k4 < 16; ++k4) {
            const int ch = (k4 + pg) & 15;
            float4 wv0 = w0[k4], wv1 = w1[k4];
            float4 a = p0[ch], b = p1[ch], c = p2[ch], d = p3[ch];
            acc[0][0] += a.x*wv0.x + a.y*wv0.y + a.z*wv0.z + a.w*wv0.w;
            acc[0][1] += a.x*wv1.x + a.y*wv1.y + a.z*wv1.z + a.w*wv1.w;
            acc[1][0] += b.x*wv0.x + b.y*wv0.y + b.z*wv0.z + b.w*wv0.w;
            acc[1][1] += b.x*wv1.x + b.y*wv1.y + b.z*wv1.z + b.w*wv1.w;
            acc[2][0] += c.x*wv0.x + c.y*wv0.y + c.z*wv0.z + c.w*wv0.w;
            acc[2][1] += c.x*wv1.x + c.y*wv1.y + c.z*wv1.z + c.w*wv1.w;
            acc[3][0] += d.x*wv0.x + d.y*wv0.y + d.z*wv0.z + d.w*wv0.w;
            acc[3][1] += d.x*wv1.x + d.y*wv1.y + d.z*wv1.z + d.w*wv1.w;
        }
    }
    __syncthreads();

    float* fls = smem;
    {
        const int pg = tid & 31;
        const int jg = tid >> 5;
        const int j0 = jg * 2;
        float bm2a = bm2[j0], bm2b = bm2[j0 + 1];
        #pragma unroll
        for (int i = 0; i < 4; ++i) {
            fls[(4 * pg + i) * 17 + j0]     = acc[i][0] + bm2a;
            fls[(4 * pg + i) * 17 + j0 + 1] = acc[i][1] + bm2b;
        }
    }
    __syncthreads();

    {
        const int el = tid >> 2, cg = tid & 3;
        const float* f0 = &fls[(el * 2 + 0) * 17];
        const float* f1 = &fls[(el * 2 + 1) * 17];
        float a0 = f0[0*4+cg], a1 = f0[1*4+cg], a2 = f0[2*4+cg], a3 = f0[3*4+cg];
        float b0 = f1[0*4+cg], b1 = f1[1*4+cg], b2 = f1[2*4+cg], b3 = f1[3*4+cg];
        float4 pp, qq, rr;
        {
            float c0, c1, c2, c3;
            c0 = f1[0]; c1 = f1[4]; c2 = f1[8]; c3 = f1[12];
            pp.x = a0*c0 + a1*c1 + a2*c2 + a3*c3;
            rr.x = b0*c0 + b1*c1 + b2*c2 + b3*c3;
            c0 = f1[1]; c1 = f1[5]; c2 = f1[9]; c3 = f1[13];
            pp.y = a0*c0 + a1*c1 + a2*c2 + a3*c3;
            rr.y = b0*c0 + b1*c1 + b2*c2 + b3*c3;
            c0 = f1[2]; c1 = f1[6]; c2 = f1[10]; c3 = f1[14];
            pp.z = a0*c0 + a1*c1 + a2*c2 + a3*c3;
            rr.z = b0*c0 + b1*c1 + b2*c2 + b3*c3;
            c0 = f1[3]; c1 = f1[7]; c2 = f1[11]; c3 = f1[15];
            pp.w = a0*c0 + a1*c1 + a2*c2 + a3*c3;
            rr.w = b0*c0 + b1*c1 + b2*c2 + b3*c3;
            c0 = f0[0]; c1 = f0[4]; c2 = f0[8]; c3 = f0[12];
            qq.x = a0*c0 + a1*c1 + a2*c2 + a3*c3;
            c0 = f0[1]; c1 = f0[5]; c2 = f0[9]; c3 = f0[13];
            qq.y = a0*c0 + a1*c1 + a2*c2 + a3*c3;
            c0 = f0[2]; c1 = f0[6]; c2 = f0[10]; c3 = f0[14];
            qq.z = a0*c0 + a1*c1 + a2*c2 + a3*c3;
            c0 = f0[3]; c1 = f0[7]; c2 = f0[11]; c3 = f0[15];
            qq.w = a0*c0 + a1*c1 + a2*c2 + a3*c3;
        }
        const int eg = e0 + el;
        const int pS = posS[eg];
        const int pD = posD[eg];
        // src slot: row-major bf16 P
        unsigned sx = (unsigned)f2bf(pp.x) | ((unsigned)f2bf(pp.y) << 16);
        unsigned sy = (unsigned)f2bf(pp.z) | ((unsigned)f2bf(pp.w) << 16);
        *(uint2*)(P2 + (size_t)pS * 16 + cg * 4) = make_uint2(sx, sy);
        // dst slot: transposed bf16 P
        unsigned short* rowD = P2 + (size_t)pD * 16;
        rowD[0 * 4 + cg] = f2bf(pp.x);
        rowD[1 * 4 + cg] = f2bf(pp.y);
        rowD[2 * 4 + cg] = f2bf(pp.z);
        rowD[3 * 4 + cg] = f2bf(pp.w);
        // QR2 (f32, CSR slots): q at src slot, r at dst slot
        *(float4*)(QR2 + (size_t)pS * 16 + cg * 4) = qq;
        *(float4*)(QR2 + (size_t)pD * 16 + cg * 4) = rr;
    }
}

// ===========================================================================
// k_nodeM — M[n] = Σ_p QR2[p] over the node's CSR range. Fully sequential,
// no index indirection (the CSR-ordered QR2 bakes the Qb/Rb select in).
// ===========================================================================
__global__ __launch_bounds__(256) void k_nodeM(
    const int* __restrict__ off, const float* __restrict__ QR2,
    float* __restrict__ M)
{
    const int tid = threadIdx.x;
    const int ni = tid >> 4, comp = tid & 15;
    const int n = blockIdx.x * 16 + ni;
    const int p0 = off[n], p1 = off[n + 1];
    float s = 0.f;
    for (int p = p0; p < p1; ++p)
        s += QR2[(size_t)p * 16 + comp];
    M[(size_t)n * 16 + comp] = s;
}

// ===========================================================================
// k_node_H — H0 = (Wd1.T @ xb) @ Wd2.T per node, stored as BF16 (packed
// per-lane layout H[n][t*4+k]). Wd2 read directly from global.
// ===========================================================================
__global__ __launch_bounds__(256) void k_node_H(
    const float* __restrict__ xb,
    const float* __restrict__ Wd1l, const float* __restrict__ Wd2l,
    unsigned short* __restrict__ H)
{
    __shared__ float tl[4][4][64];
    const int tid = threadIdx.x;
    const int w = __builtin_amdgcn_readfirstlane(tid >> 6);
    const int t = tid & 63;

    float wd1[16];
    #pragma unroll
    for (int i = 0; i < 16; ++i) wd1[i] = Wd1l[i];
    const float* wrow = Wd2l + t * 64;

    for (int rep = 0; rep < 4; ++rep) {
        const int n = blockIdx.x * 16 + w * 4 + rep;
        float xv[4];
        #pragma unroll
        for (int j = 0; j < 4; ++j) xv[j] = xb[(size_t)n * HID + j * 64 + t];
        #pragma unroll
        for (int i = 0; i < 4; ++i)
            tl[w][i][t] = wd1[0 + i] * xv[0] + wd1[4 + i] * xv[1] +
                          wd1[8 + i] * xv[2] + wd1[12 + i] * xv[3];
        float a0 = 0, a1 = 0, a2 = 0, a3 = 0;
        #pragma unroll
        for (int f = 0; f < 64; f += 4) {
            float4 wv = *(const float4*)(wrow + f);
            float4 t0 = *(const float4*)&tl[w][0][f];
            float4 t1 = *(const float4*)&tl[w][1][f];
            float4 t2 = *(const float4*)&tl[w][2][f];
            float4 t3 = *(const float4*)&tl[w][3][f];
            a0 += t0.x * wv.x + t0.y * wv.y + t0.z * wv.z + t0.w * wv.w;
            a1 += t1.x * wv.x + t1.y * wv.y + t1.z * wv.z + t1.w * wv.w;
            a2 += t2.x * wv.x + t2.y * wv.y + t2.z * wv.z + t2.w * wv.w;
            a3 += t3.x * wv.x + t3.y * wv.y + t3.z * wv.z + t3.w * wv.w;
        }
        unsigned lo = (unsigned)f2bf(a0) | ((unsigned)f2bf(a1) << 16);
        unsigned hi = (unsigned)f2bf(a2) | ((unsigned)f2bf(a3) << 16);
        *(uint2*)(H + (size_t)n * HID + (t << 2)) = make_uint2(lo, hi);
    }
}

// ===========================================================================
// sheaf gather — round-8 form (measured best). ALL scalar streams have
// statically-known sequential addresses (inc2[p], P2 row p); the only
// dependent load is H. Pair unroll; DO NOT restructure (rounds 0-6).
// ===========================================================================
__device__ __forceinline__ void sheaf_apply_bf(const unsigned pr[8], uint2 u, float acc[4])
{
    const float h0 = __uint_as_float(u.x << 16);
    const float h1 = __uint_as_float(u.x & 0xFFFF0000u);
    const float h2 = __uint_as_float(u.y << 16);
    const float h3 = __uint_as_float(u.y & 0xFFFF0000u);
    #pragma unroll
    for (int j = 0; j < 4; ++j) {
        const unsigned d0 = pr[j * 2 + 0], d1 = pr[j * 2 + 1];
        const float q0 = __uint_as_float(d0 << 16);
        const float q1 = __uint_as_float(d0 & 0xFFFF0000u);
        const float q2 = __uint_as_float(d1 << 16);
        const float q3 = __uint_as_float(d1 & 0xFFFF0000u);
        acc[j] -= q0 * h0 + q1 * h1 + q2 * h2 + q3 * h3;
    }
}

__device__ __forceinline__ void sheaf_gather(
    const int* __restrict__ inc2,
    const unsigned short* __restrict__ P2, const unsigned short* __restrict__ Hin,
    int p0, int p1, int t, float acc[4])
{
    int p = p0;
    for (; p + 2 <= p1; p += 2) {
        const int oA = __builtin_amdgcn_readfirstlane(inc2[p]);
        const int oB = __builtin_amdgcn_readfirstlane(inc2[p + 1]);
        const uint2 uA = *(const uint2*)(Hin + (size_t)oA * HID + (t << 2));
        const uint2 uB = *(const uint2*)(Hin + (size_t)oB * HID + (t << 2));
        const unsigned* pr = (const unsigned*)P2 + (size_t)p * 8;
        unsigned da[8], db[8];
        #pragma unroll
        for (int i = 0; i < 8; ++i) da[i] = pr[i];
        #pragma unroll
        for (int i = 0; i < 8; ++i) db[i] = pr[8 + i];
        sheaf_apply_bf(da, uA, acc);
        sheaf_apply_bf(db, uB, acc);
    }
    if (p < p1) {
        const int o = __builtin_amdgcn_readfirstlane(inc2[p]);
        const uint2 u = *(const uint2*)(Hin + (size_t)o * HID + (t << 2));
        const unsigned* pr = (const unsigned*)P2 + (size_t)p * 8;
        unsigned da[8];
        #pragma unroll
        for (int i = 0; i < 8; ++i) da[i] = pr[i];
        sheaf_apply_bf(da, u, acc);
    }
}

// ===========================================================================
// k_sheaf0 — layer 0: LH gather + xb update + fused next-layer H (bf16 out).
// Wd2 from global (L2-resident); LDS = tl only (4 KB); barrier-free.
// ===========================================================================
__global__ __launch_bounds__(256) void k_sheaf0(
    const int* __restrict__ inc2, const int* __restrict__ off,
    const unsigned short* __restrict__ P2, const float* __restrict__ M,
    const unsigned short* __restrict__ Hin, float* __restrict__ h,
    unsigned short* __restrict__ Hout,
    const float* __restrict__ Wd1l, const float* __restrict__ Wd2l)
{
    __shared__ float tl[4][4][64];
    const int tid = threadIdx.x;
    const int w = __builtin_amdgcn_readfirstlane(tid >> 6);
    const int t = tid & 63;

    float wd1[16];
    #pragma unroll
    for (int i = 0; i < 16; ++i) wd1[i] = Wd1l[i];

    const int n = blockIdx.x * 4 + w;
    const uint2 un = *(const uint2*)(Hin + (size_t)n * HID + (t << 2));
    float Hn[4];
    Hn[0] = __uint_as_float(un.x << 16);
    Hn[1] = __uint_as_float(un.x & 0xFFFF0000u);
    Hn[2] = __uint_as_float(un.y << 16);
    Hn[3] = __uint_as_float(un.y & 0xFFFF0000u);
    float Mn[16];
    #pragma unroll
    for (int c = 0; c < 16; ++c) Mn[c] = M[(size_t)n * 16 + c];

    float acc[4];
    #pragma unroll
    for (int j = 0; j < 4; ++j)
        acc[j] = Mn[j*4+0]*Hn[0] + Mn[j*4+1]*Hn[1] + Mn[j*4+2]*Hn[2] + Mn[j*4+3]*Hn[3];

    const int p0 = __builtin_amdgcn_readfirstlane(off[n]);
    const int p1 = __builtin_amdgcn_readfirstlane(off[n + 1]);
    sheaf_gather(inc2, P2, Hin, p0, p1, t, acc);

    float xv[4];
    #pragma unroll
    for (int j = 0; j < 4; ++j) {
        size_t idx = (size_t)n * HID + j * 64 + t;
        float vv = h[idx] - fmaxf(acc[j], 0.f);
        h[idx] = vv;
        xv[j] = vv;
    }

    #pragma unroll
    for (int i = 0; i < 4; ++i)
        tl[w][i][t] = wd1[0 + i] * xv[0] + wd1[4 + i] * xv[1] +
                      wd1[8 + i] * xv[2] + wd1[12 + i] * xv[3];
    // no __syncthreads(): tl[w] is wave-private; DS ops complete in order.
    const float* wrow = Wd2l + t * 64;
    float a0 = 0, a1 = 0, a2 = 0, a3 = 0;
    #pragma unroll
    for (int f = 0; f < 64; f += 4) {
        float4 wv = *(const float4*)(wrow + f);
        float4 t0 = *(const float4*)&tl[w][0][f];
        float4 t1 = *(const float4*)&tl[w][1][f];
        float4 t2 = *(const float4*)&tl[w][2][f];
        float4 t3 = *(const float4*)&tl[w][3][f];
        a0 += t0.x * wv.x + t0.y * wv.y + t0.z * wv.z + t0.w * wv.w;
        a1 += t1.x * wv.x + t1.y * wv.y + t1.z * wv.z + t1.w * wv.w;
        a2 += t2.x * wv.x + t2.y * wv.y + t2.z * wv.z + t2.w * wv.w;
        a3 += t3.x * wv.x + t3.y * wv.y + t3.z * wv.z + t3.w * wv.w;
    }
    unsigned lo = (unsigned)f2bf(a0) | ((unsigned)f2bf(a1) << 16);
    unsigned hi = (unsigned)f2bf(a2) | ((unsigned)f2bf(a3) << 16);
    *(uint2*)(Hout + (size_t)n * HID + (t << 2)) = make_uint2(lo, hi);
}

// ===========================================================================
// k_sheaf1 — layer 1: LH gather + xb update only. ZERO LDS.
// ===========================================================================
__global__ __launch_bounds__(256) void k_sheaf1(
    const int* __restrict__ inc2, const int* __restrict__ off,
    const unsigned short* __restrict__ P2, const float* __restrict__ M,
    const unsigned short* __restrict__ Hin, float* __restrict__ h)
{
    const int tid = threadIdx.x;
    const int w = __builtin_amdgcn_readfirstlane(tid >> 6);
    const int t = tid & 63;
    const int n = blockIdx.x * 4 + w;

    const uint2 un = *(const uint2*)(Hin + (size_t)n * HID + (t << 2));
    float Hn[4];
    Hn[0] = __uint_as_float(un.x << 16);
    Hn[1] = __uint_as_float(un.x & 0xFFFF0000u);
    Hn[2] = __uint_as_float(un.y << 16);
    Hn[3] = __uint_as_float(un.y & 0xFFFF0000u);
    float Mn[16];
    #pragma unroll
    for (int c = 0; c < 16; ++c) Mn[c] = M[(size_t)n * 16 + c];

    float acc[4];
    #pragma unroll
    for (int j = 0; j < 4; ++j)
        acc[j] = Mn[j*4+0]*Hn[0] + Mn[j*4+1]*Hn[1] + Mn[j*4+2]*Hn[2] + Mn[j*4+3]*Hn[3];

    const int p0 = __builtin_amdgcn_readfirstlane(off[n]);
    const int p1 = __builtin_amdgcn_readfirstlane(off[n + 1]);
    sheaf_gather(inc2, P2, Hin, p0, p1, t, acc);

    #pragma unroll
    for (int j = 0; j < 4; ++j) {
        size_t idx = (size_t)n * HID + j * 64 + t;
        h[idx] = h[idx] - fmaxf(acc[j], 0.f);
    }
}

// ===========================================================================
// k_out1: t1o = relu(xb @ Wo1.T + bo1).  grid (N/64, 4).
// ===========================================================================
__global__ __launch_bounds__(256, 4) void k_out1(
    const float* __restrict__ xb, const float* __restrict__ Wo1, const float* __restrict__ bo1,
    float* __restrict__ t1o)
{
    __shared__ float xr[64 * 129];
    const int tid  = threadIdx.x;
    const int w    = __builtin_amdgcn_readfirstlane(tid >> 6);
    const int lane = tid & 63;
    const int node0 = blockIdx.x * 64;
    const int cbase = blockIdx.y * 16 + w * 4;
    const int g = min(node0 + lane, NN - 1);
    const bool valid = (node0 + lane) < NN;

    float acc[4] = {0.f, 0.f, 0.f, 0.f};

    for (int j = 0; j < 2; ++j) {
        __syncthreads();
        for (int i = tid; i < 2048; i += 256) {
            int n = i >> 5, k4 = i & 31;
            int gr = min(node0 + n, NN - 1);
            float4 v = ((const float4*)xb)[(size_t)gr * 64 + j * 32 + k4];
            float* d = &xr[n * 129 + k4 * 4];
            d[0] = v.x; d[1] = v.y; d[2] = v.z; d[3] = v.w;
        }
        __syncthreads();
        for (int kt = 0; kt < 32; ++kt) {
            float x0 = xr[lane * 129 + kt * 4 + 0];
            float x1 = xr[lane * 129 + kt * 4 + 1];
            float x2 = xr[lane * 129 + kt * 4 + 2];
            float x3 = xr[lane * 129 + kt * 4 + 3];
            #pragma unroll
            for (int cc = 0; cc < 4; ++cc) {
                const float* wr = Wo1 + (size_t)(cbase + cc) * HID + j * 128 + kt * 4;
                acc[cc] += x0 * wr[0] + x1 * wr[1] + x2 * wr[2] + x3 * wr[3];
            }
        }
    }
    if (valid) {
        float4 v;
        v.x = fmaxf(acc[0] + bo1[cbase + 0], 0.f);
        v.y = fmaxf(acc[1] + bo1[cbase + 1], 0.f);
        v.z = fmaxf(acc[2] + bo1[cbase + 2], 0.f);
        v.w = fmaxf(acc[3] + bo1[cbase + 3], 0.f);
        *(float4*)(t1o + (size_t)g * MH + cbase) = v;
    }
}

// ===========================================================================
// k_out2: out = t1o @ Wo2.T + bo2.
// ===========================================================================
__global__ __launch_bounds__(256, 4) void k_out2(
    const float* __restrict__ t1o, const float* __restrict__ Wo2, const float* __restrict__ bo2,
    float* __restrict__ out)
{
    __shared__ float ts[64 * 65];
    const int tid  = threadIdx.x;
    const int lane = tid & 63;
    const int node0 = blockIdx.x * 64;
    const int g = min(node0 + lane, NN - 1);
    const bool valid = (node0 + lane) < NN;

    for (int i = tid; i < 1024; i += 256) {
        int n = i >> 4, k4 = i & 15;
        int gr = min(node0 + n, NN - 1);
        float4 v = ((const float4*)t1o)[(size_t)gr * 16 + k4];
        float* d = &ts[n * 65 + k4 * 4];
        d[0] = v.x; d[1] = v.y; d[2] = v.z; d[3] = v.w;
    }
    __syncthreads();

    float acc[16];
    #pragma unroll
    for (int i = 0; i < 16; ++i) acc[i] = 0.f;
    for (int kt = 0; kt < 8; ++kt) {
        float tv[8];
        #pragma unroll
        for (int i = 0; i < 8; ++i) tv[i] = ts[lane * 65 + kt * 8 + i];
        #pragma unroll
        for (int jj = 0; jj < 16; ++jj) {
            const float* wr = Wo2 + (size_t)jj * MH + kt * 8;
            acc[jj] += tv[0]*wr[0] + tv[1]*wr[1] + tv[2]*wr[2] + tv[3]*wr[3]
                     + tv[4]*wr[4] + tv[5]*wr[5] + tv[6]*wr[6] + tv[7]*wr[7];
        }
    }
    if (valid) {
        float* op = out + (size_t)g * OUT_D;
        #pragma unroll
        for (int c4 = 0; c4 < 4; ++c4) {
            float4 v;
            v.x = acc[c4*4+0] + bo2[c4*4+0];
            v.y = acc[c4*4+1] + bo2[c4*4+1];
            v.z = acc[c4*4+2] + bo2[c4*4+2];
            v.w = acc[c4*4+3] + bo2[c4*4+3];
            *(float4*)(op + c4 * 4) = v;
        }
    }
}

// ---------------------------------------------------------------------------
// Workspace (~89.2 MB, unchanged total).
//   QR2 (f32, 2E*16 = 25.6MB) starts at H0 and spans 5.12MB into H1 — dead
//   regions at that time (t1 consumed, H0b/H1b written later, posS/posD at
//   H1+14MB, bsum dead after scan). AB2 (packed bf16 pairs, 5.12MB) sits in
//   the old AB region. P2 (bf16, 12.8MB) in the old P region.
// ---------------------------------------------------------------------------
extern "C" void kernel_launch(void* const* d_in, const int* in_sizes, int n_in,
                              void* d_out, int out_size, void* d_ws, size_t ws_size,
                              hipStream_t stream)
{
    const float* x    = (const float*)d_in[0];
    const int*   ei   = (const int*)d_in[1];
    const float* Win1 = (const float*)d_in[2];
    const float* bin1 = (const float*)d_in[3];
    const float* Win2 = (const float*)d_in[4];
    const float* bin2 = (const float*)d_in[5];
    const float* Wm1  = (const float*)d_in[6];
    const float* bm1  = (const float*)d_in[7];
    const float* Wm2  = (const float*)d_in[8];
    const float* bm2  = (const float*)d_in[9];
    const float* Wd1  = (const float*)d_in[10];
    const float* Wd2  = (const float*)d_in[11];
    const float* Wo1  = (const float*)d_in[12];
    const float* bo1  = (const float*)d_in[13];
    const float* Wo2  = (const float*)d_in[14];
    const float* bo2  = (const float*)d_in[15];
    float* out = (float*)d_out;

    float* ws = (float*)d_ws;
    float* h  = ws;                            // N*256
    float* ABf = h  + (size_t)NN * HID;        // N*128 region (AB2 packed)
    float* H0 = ABf + (size_t)NN * 128;        // N*256 region
    float* H1 = H0 + (size_t)NN * HID;         // N*256 region
    float* Pf = H1 + (size_t)NN * HID;         // E*16 region -> bf16 P2
    float* M  = Pf + (size_t)EE * 16;          // N*16
    int* deg    = (int*)(M + (size_t)NN * 16); // N
    int* off    = deg + NN;                    // N+1
    int* cursor = off + NN + 1;                // N
    int* inc2   = cursor + NN;                 // 2E (old inc slot unused)
    float* t1  = H0;                           // alias
    float* t1o = H1;                           // alias
    float* QR2 = H0;                           // 2E*16 f32, spans into H1
    unsigned short* H0b = (unsigned short*)H0; // bf16 view (first half)
    unsigned short* H1b = (unsigned short*)H1;
    unsigned short* P2  = (unsigned short*)Pf; // bf16 CSR-ordered P (2E*16)
    unsigned* AB2 = (unsigned*)ABf;            // N*64 packed {a,b} bf16
    int* bsum = (int*)H1;                      // 250 ints, dead at scan time
    int* posS = (int*)(H1 + 3500000);          // E ints @ H1+14MB (dead tail)
    int* posD = posS + EE;                     // E ints

    const int NB = (NN + 63) / 64;             // 313

    // CSR build (parallel scan: 250x80 local -> 1-block top -> add base)
    hipMemsetAsync(deg, 0, NN * sizeof(int), stream);
    k_deg<<<(EE + 255) / 256, 256, 0, stream>>>(ei, deg);
    k_scan_a<<<250, 128, 0, stream>>>(deg, off, bsum);
    k_scan_b<<<1, 256, 0, stream>>>(bsum);
    k_scan_c<<<(NN + 255) / 256, 256, 0, stream>>>(bsum, off, cursor);
    k_scatter<<<(EE + 255) / 256, 256, 0, stream>>>(ei, cursor, inc2, posS, posD);

    // node MLP + per-edge P2/QR2 (CSR-ordered) + sequential M reduction
    k_mlp1<<<dim3(NB, 4), 256, 0, stream>>>(x, Win1, bin1, t1);
    k_mlp2<<<dim3(NB, 4), 256, 0, stream>>>(t1, Win2, bin2, h);
    k_mlp3<<<dim3(NB, 4), 256, 0, stream>>>(h, Wm1, AB2);
    k_edge_msg<<<EE / 64, 256, 0, stream>>>(ei, AB2, bm1, Wm2, bm2, P2, posS, posD, QR2);
    k_nodeM<<<NN / 16, 256, 0, stream>>>(off, QR2, M);

    // diffusion (H in bf16 packed per-lane layout; P2 bf16 CSR-ordered)
    k_node_H<<<NN / 16, 256, 0, stream>>>(h, Wd1, Wd2, H0b);
    k_sheaf0<<<NN / 4, 256, 0, stream>>>(inc2, off, P2, M, H0b, h, H1b,
                                         Wd1 + 16, Wd2 + 4096);
    k_sheaf1<<<NN / 4, 256, 0, stream>>>(inc2, off, P2, M, H1b, h);

    // output MLP
    k_out1<<<dim3(NB, 4), 256, 0, stream>>>(h, Wo1, bo1, t1o);
    k_out2<<<NB, 256, 0, stream>>>(t1o, Wo2, bo2, out);
}